// Round 3
// baseline (405.717 us; speedup 1.0000x reference)
//
#include <hip/hip_runtime.h>
#include <hip/hip_bf16.h>
#include <hip/hip_cooperative_groups.h>
#include <math.h>

namespace cg = cooperative_groups;

#define LTOK 512
#define DDIM 512
#define NEXP 32
#define HDIM 512

typedef __attribute__((ext_vector_type(8))) short short8;
typedef __attribute__((ext_vector_type(4))) float floatx4;

// round-to-nearest-even fp32->bf16, packed pair: low16 = rne(a), high16 = rne(b)
__device__ __forceinline__ unsigned bpack(float a, float b) {
    unsigned ua = __float_as_uint(a), ub = __float_as_uint(b);
    ua += 0x7FFFu + ((ua >> 16) & 1u);
    ub += 0x7FFFu + ((ub >> 16) & 1u);
    return (ua >> 16) | (ub & 0xFFFF0000u);
}

// Raw barrier WITHOUT the compiler's s_waitcnt vmcnt(0) drain (fallback path).
#define RAW_BARRIER() do { \
    asm volatile("s_waitcnt lgkmcnt(0)" ::: "memory"); \
    __builtin_amdgcn_s_barrier(); \
} while (0)

// ws layout (bytes):
//   [0, 4K)        easgn: int[1024]   easgn[2t+k] = expert of token t's k-th pick
//   [4K, 8K)       wts:   float[1024] = routing weight * per_expert_scale
//   [8K, +512K)    xb:    512x512 bf16 (x rounded to bf16)
//   [532480, +1M)  act:   1024x512 bf16 (slot-indexed activated gate output)

// ============================================================================
// FUSED cooperative kernel: grid 1024 x 256 = 4 blocks/CU x 256 CU (exactly
// co-resident). bid -> (e = bid>>5, tile = bid&31); tile is the h-tile in the
// gates phase and the d-tile in the linear phase (same expert both phases ->
// the self-select scan is computed ONCE and reused from LDS).
// Key overlap: G register-stage issued at t=0 (64 MB download runs under the
// router phase + sync-1); Wl register-stage issued after the gates loop (32 MB
// runs under gates stragglers + sync-2). No early returns (coop correctness).
// ============================================================================
__global__ __launch_bounds__(256, 4) void moe_fused(
    const float* __restrict__ x, const float* __restrict__ rs,
    const float* __restrict__ Wr, const float* __restrict__ pes,
    const float* __restrict__ G, const float* __restrict__ Wl,
    int* __restrict__ easgn, float* __restrict__ wts,
    short* __restrict__ xb, short* __restrict__ act,
    float* __restrict__ out)
{
    cg::grid_group gg = cg::this_grid();

    const int bid  = blockIdx.x;        // 0..1023
    const int e    = bid >> 5;          // expert
    const int tile = bid & 31;          // h-tile (gates) / d-tile (linear)
    const int tid  = threadIdx.x;
    const int wv   = tid >> 6;
    const int lane = tid & 63;
    const int n    = lane & 15;
    const int quad = lane >> 4;
    const int g    = wv & 1;            // gate index (gates phase)
    const int kh   = wv >> 1;           // K half (gates phase)
    const int h0   = tile * 16;
    const int d0   = tile * 16;

    __shared__ float red[4][2][4][64];   // 8 KB  (gates + linear)
    __shared__ int   toks[LTOK];         // 2 KB  (shared scan result)
    __shared__ float wsl[LTOK];          // 2 KB
    __shared__ int   lcnt;
    __shared__ float ri[DDIM];           // 2 KB  (router)
    __shared__ float sred[4];
    __shared__ float lpart[8][NEXP];     // 1 KB
    __shared__ float lgs[NEXP];

    // ---- issue G register-stage NOW (overlaps router phase + sync-1) ----
    const float* Gl = G + ((size_t)((e * 2 + g) * HDIM) + h0 + n) * DDIM + kh * 256 + quad * 8;
    floatx4 u0[8], u1[8];
#pragma unroll
    for (int ks = 0; ks < 8; ++ks) {
        u0[ks] = *(const floatx4*)(Gl + ks * 32);
        u1[ks] = *(const floatx4*)(Gl + ks * 32 + 4);
    }

    // ================= phase 0: router (blocks 0..511, one token each) =====
    if (bid < LTOK) {
        const int t = bid;
        float xv[2];
        float ss = 0.f;
#pragma unroll
        for (int j = 0; j < 2; ++j) {
            xv[j] = x[t * DDIM + j * 256 + tid];
            ss += xv[j] * xv[j];
        }
#pragma unroll
        for (int j = 0; j < 2; ++j) {
            xb[t * DDIM + j * 256 + tid] = (short)(bpack(xv[j], 0.f) & 0xFFFFu);
            out[t * DDIM + j * 256 + tid] = 0.f;
        }

#pragma unroll
        for (int o = 32; o > 0; o >>= 1) ss += __shfl_xor(ss, o);
        if (lane == 0) sred[wv] = ss;
        __syncthreads();
        ss = (sred[0] + sred[1]) + (sred[2] + sred[3]);
        const float var = ss * (1.0f / 512.0f);
        const float coef = rsqrtf(var + 1e-6f) * rsqrtf(512.0f);

#pragma unroll
        for (int j = 0; j < 2; ++j) {
            const int d = j * 256 + tid;
            ri[d] = xv[j] * coef * rs[d];
        }
        __syncthreads();

        // logits: tid&31 -> expert, tid>>5 -> 1/8th of D (64 d each)
        const int er  = tid & 31;
        const int seg = tid >> 5;
        const int dbeg = seg * 64;
        float l0 = 0.f, l1 = 0.f, l2 = 0.f, l3 = 0.f;
#pragma unroll 4
        for (int d = dbeg; d < dbeg + 64; d += 4) {
            l0 = fmaf(ri[d + 0], Wr[(d + 0) * NEXP + er], l0);
            l1 = fmaf(ri[d + 1], Wr[(d + 1) * NEXP + er], l1);
            l2 = fmaf(ri[d + 2], Wr[(d + 2) * NEXP + er], l2);
            l3 = fmaf(ri[d + 3], Wr[(d + 3) * NEXP + er], l3);
        }
        lpart[seg][er] = (l0 + l1) + (l2 + l3);
        __syncthreads();

        if (tid < NEXP) {
            float v = 0.f;
#pragma unroll
            for (int s = 0; s < 8; ++s) v += lpart[s][tid];
            lgs[tid] = v;
        }
        __syncthreads();

        if (tid == 0) {
            int i0 = 0; float m0 = lgs[0];
            for (int i = 1; i < NEXP; ++i) if (lgs[i] > m0) { m0 = lgs[i]; i0 = i; }
            int i1 = -1; float m1 = -1e30f;
            for (int i = 0; i < NEXP; ++i) if (i != i0 && lgs[i] > m1) { m1 = lgs[i]; i1 = i; }
            // softmax denom cancels against renorm: top-2 logits suffice
            const float e1 = expf(m1 - m0);
            const float inv = 1.0f / (1.0f + e1);
            easgn[2 * t]     = i0;
            easgn[2 * t + 1] = i1;
            wts[2 * t]     = inv * pes[i0];
            wts[2 * t + 1] = e1 * inv * pes[i1];
        }
    }

    gg.sync();   // ======================= sync 1 ===========================

    // ================= phase 1: gates =====================================
    // scan (computed once, reused by linear phase)
    const int4  eg  = ((const int4*)easgn)[tid];
    const float4 wt4 = ((const float4*)wts)[tid];
    if (tid == 0) lcnt = 0;
    __syncthreads();
    if (eg.x == e) { int p = atomicAdd(&lcnt, 1); toks[p] = 4 * tid;     wsl[p] = wt4.x; }
    if (eg.y == e) { int p = atomicAdd(&lcnt, 1); toks[p] = 4 * tid + 1; wsl[p] = wt4.y; }
    if (eg.z == e) { int p = atomicAdd(&lcnt, 1); toks[p] = 4 * tid + 2; wsl[p] = wt4.z; }
    if (eg.w == e) { int p = atomicAdd(&lcnt, 1); toks[p] = 4 * tid + 3; wsl[p] = wt4.w; }
    __syncthreads();
    const int Ne = lcnt;

    // pack B fragments from the (long-landed) G registers
    short8 Bg[8];
#pragma unroll
    for (int ks = 0; ks < 8; ++ks) {
        union { short8 s; unsigned u[4]; } B;
        B.u[0] = bpack(u0[ks].x, u0[ks].y);
        B.u[1] = bpack(u0[ks].z, u0[ks].w);
        B.u[2] = bpack(u1[ks].x, u1[ks].y);
        B.u[3] = bpack(u1[ks].z, u1[ks].w);
        Bg[ks] = B.s;
    }

    if (Ne > 0) {
        const short* xbh = xb + kh * 256;
        for (int mb = 0; mb < Ne; mb += 32) {
            int arow[2];
#pragma unroll
            for (int i = 0; i < 2; ++i) {
                int s = mb + i * 16 + n;
                arow[i] = toks[s < Ne ? s : Ne - 1] >> 1;   // token index
            }
            floatx4 acc[2] = {};
#pragma unroll
            for (int ks = 0; ks < 8; ++ks) {
                const int ko = ks * 32 + quad * 8;
#pragma unroll
                for (int i = 0; i < 2; ++i) {
                    const short8 A = *(const short8*)(xbh + (size_t)arow[i] * DDIM + ko);
                    acc[i] = __builtin_amdgcn_mfma_f32_16x16x32_bf16(A, Bg[ks], acc[i], 0, 0, 0);
                }
            }
#pragma unroll
            for (int i = 0; i < 2; ++i)
#pragma unroll
                for (int r = 0; r < 4; ++r)
                    red[wv][i][r][lane] = acc[i][r];
            __syncthreads();

            // epilogue: wave handles m-tile (wv&1), regs {2u,2u+1}, u=wv>>1.
            {
                const int i = wv & 1;
                const int u = wv >> 1;
#pragma unroll
                for (int rr = 0; rr < 2; ++rr) {
                    const int r = u * 2 + rr;
                    const int s = mb + i * 16 + quad * 4 + r;
                    if (s < Ne) {
                        const int a = toks[s];   // slot id = act row
                        const float g0 = red[0][i][r][lane] + red[2][i][r][lane];
                        const float g1 = red[1][i][r][lane] + red[3][i][r][lane];
                        const float uu = 0.7978845608f * (g0 + 0.044715f * g0 * g0 * g0);
                        const float sg = 1.0f / (1.0f + __expf(-2.0f * uu));
                        const float v = g0 * sg * g1;
                        act[(size_t)a * HDIM + h0 + n] = (short)(bpack(v, 0.f) & 0xFFFFu);
                    }
                }
            }
            __syncthreads();
        }
    }

    // ---- issue Wl register-stage (overlaps gates stragglers + sync-2) ----
    const float* Wbase = Wl + ((size_t)e * HDIM + wv * 128 + quad * 8) * DDIM + d0 + n;
    float w[32];
#pragma unroll
    for (int ks = 0; ks < 4; ++ks)
#pragma unroll
        for (int j = 0; j < 8; ++j)
            w[ks * 8 + j] = Wbase[(size_t)(ks * 32 + j) * DDIM];

    gg.sync();   // ======================= sync 2 ===========================

    // ================= phase 2: linear ====================================
    short8 Bl[4];
#pragma unroll
    for (int ks = 0; ks < 4; ++ks) {
        union { short8 s; unsigned u[4]; } B;
        B.u[0] = bpack(w[ks * 8 + 0], w[ks * 8 + 1]);
        B.u[1] = bpack(w[ks * 8 + 2], w[ks * 8 + 3]);
        B.u[2] = bpack(w[ks * 8 + 4], w[ks * 8 + 5]);
        B.u[3] = bpack(w[ks * 8 + 6], w[ks * 8 + 7]);
        Bl[ks] = B.s;
    }

    if (Ne > 0) {
        for (int mb = 0; mb < Ne; mb += 32) {
            int arow[2];
#pragma unroll
            for (int i = 0; i < 2; ++i) {
                int s = mb + i * 16 + n;
                arow[i] = toks[s < Ne ? s : Ne - 1];   // slot id = act row
            }
            floatx4 acc[2] = {};
#pragma unroll
            for (int ks = 0; ks < 4; ++ks) {
                const int ko = wv * 128 + ks * 32 + quad * 8;
#pragma unroll
                for (int i = 0; i < 2; ++i) {
                    const short8 A = *(const short8*)(act + (size_t)arow[i] * HDIM + ko);
                    acc[i] = __builtin_amdgcn_mfma_f32_16x16x32_bf16(A, Bl[ks], acc[i], 0, 0, 0);
                }
            }
#pragma unroll
            for (int i = 0; i < 2; ++i)
#pragma unroll
                for (int r = 0; r < 4; ++r)
                    red[wv][i][r][lane] = acc[i][r];
            __syncthreads();

            {
                const int i = wv & 1;
                const int u = wv >> 1;
#pragma unroll
                for (int rr = 0; rr < 2; ++rr) {
                    const int r = u * 2 + rr;
                    const int s = mb + i * 16 + quad * 4 + r;
                    if (s < Ne) {
                        const int slot = toks[s];
                        const float v = ((red[0][i][r][lane] + red[1][i][r][lane]) +
                                         (red[2][i][r][lane] + red[3][i][r][lane])) * wsl[s];
                        atomicAdd(&out[(size_t)(slot >> 1) * DDIM + d0 + n], v);
                    }
                }
            }
            __syncthreads();
        }
    }
}

// ============================================================================
// Fallback path: the proven R2 three-kernel pipeline (used only if the
// cooperative launch is rejected by the runtime/capture).
// ============================================================================
__global__ __launch_bounds__(256) void router_kernel(
    const float* __restrict__ x, const float* __restrict__ rs,
    const float* __restrict__ Wr, const float* __restrict__ pes,
    int* __restrict__ easgn, float* __restrict__ wts,
    short* __restrict__ xb, float* __restrict__ out)
{
    const int t = blockIdx.x;
    const int tid = threadIdx.x;
    const int lane = tid & 63;
    const int wv = tid >> 6;

    float xv[2];
    float ss = 0.f;
#pragma unroll
    for (int j = 0; j < 2; ++j) {
        xv[j] = x[t * DDIM + j * 256 + tid];
        ss += xv[j] * xv[j];
    }
#pragma unroll
    for (int j = 0; j < 2; ++j) {
        xb[t * DDIM + j * 256 + tid] = (short)(bpack(xv[j], 0.f) & 0xFFFFu);
        out[t * DDIM + j * 256 + tid] = 0.f;
    }

#pragma unroll
    for (int o = 32; o > 0; o >>= 1) ss += __shfl_xor(ss, o);
    __shared__ float sred[4];
    if (lane == 0) sred[wv] = ss;
    __syncthreads();
    ss = (sred[0] + sred[1]) + (sred[2] + sred[3]);
    const float var = ss * (1.0f / 512.0f);
    const float coef = rsqrtf(var + 1e-6f) * rsqrtf(512.0f);

    __shared__ float ri[DDIM];
#pragma unroll
    for (int j = 0; j < 2; ++j) {
        const int d = j * 256 + tid;
        ri[d] = xv[j] * coef * rs[d];
    }
    __syncthreads();

    const int e = tid & 31;
    const int seg = tid >> 5;
    const int dbeg = seg * 64;
    float l0 = 0.f, l1 = 0.f, l2 = 0.f, l3 = 0.f;
#pragma unroll 4
    for (int d = dbeg; d < dbeg + 64; d += 4) {
        l0 = fmaf(ri[d + 0], Wr[(d + 0) * NEXP + e], l0);
        l1 = fmaf(ri[d + 1], Wr[(d + 1) * NEXP + e], l1);
        l2 = fmaf(ri[d + 2], Wr[(d + 2) * NEXP + e], l2);
        l3 = fmaf(ri[d + 3], Wr[(d + 3) * NEXP + e], l3);
    }
    __shared__ float lpart[8][NEXP];
    lpart[seg][e] = (l0 + l1) + (l2 + l3);
    __syncthreads();

    __shared__ float lgs[NEXP];
    if (tid < NEXP) {
        float v = 0.f;
#pragma unroll
        for (int s = 0; s < 8; ++s) v += lpart[s][tid];
        lgs[tid] = v;
    }
    __syncthreads();

    if (tid == 0) {
        int i0 = 0; float m0 = lgs[0];
        for (int i = 1; i < NEXP; ++i) if (lgs[i] > m0) { m0 = lgs[i]; i0 = i; }
        int i1 = -1; float m1 = -1e30f;
        for (int i = 0; i < NEXP; ++i) if (i != i0 && lgs[i] > m1) { m1 = lgs[i]; i1 = i; }
        const float e1 = expf(m1 - m0);
        const float inv = 1.0f / (1.0f + e1);
        easgn[2 * t]     = i0;
        easgn[2 * t + 1] = i1;
        wts[2 * t]     = inv * pes[i0];
        wts[2 * t + 1] = e1 * inv * pes[i1];
    }
}

__global__ __launch_bounds__(256, 4) void gates_kernel(
    const short* __restrict__ xb, const float* __restrict__ G,
    const int* __restrict__ easgn, short* __restrict__ act)
{
    const int e  = blockIdx.y;
    const int h0 = blockIdx.x * 16;
    const int tid = threadIdx.x;
    const int wv   = tid >> 6;
    const int g    = wv & 1;
    const int kh   = wv >> 1;
    const int lane = tid & 63;
    const int n    = lane & 15;
    const int quad = lane >> 4;

    __shared__ float red[4][2][4][64];
    __shared__ int toks[LTOK];
    __shared__ int lcnt;

    const int4 eg = ((const int4*)easgn)[tid];

    const float* Gl = G + ((size_t)((e * 2 + g) * HDIM) + h0 + n) * DDIM + kh * 256 + quad * 8;
    floatx4 u0[8], u1[8];
#pragma unroll
    for (int ks = 0; ks < 8; ++ks) {
        u0[ks] = *(const floatx4*)(Gl + ks * 32);
        u1[ks] = *(const floatx4*)(Gl + ks * 32 + 4);
    }

    if (tid == 0) lcnt = 0;
    RAW_BARRIER();
    if (eg.x == e) { int p = atomicAdd(&lcnt, 1); toks[p] = 4 * tid; }
    if (eg.y == e) { int p = atomicAdd(&lcnt, 1); toks[p] = 4 * tid + 1; }
    if (eg.z == e) { int p = atomicAdd(&lcnt, 1); toks[p] = 4 * tid + 2; }
    if (eg.w == e) { int p = atomicAdd(&lcnt, 1); toks[p] = 4 * tid + 3; }
    RAW_BARRIER();
    const int Ne = lcnt;
    if (Ne == 0) return;

    short8 Bg[8];
#pragma unroll
    for (int ks = 0; ks < 8; ++ks) {
        union { short8 s; unsigned u[4]; } B;
        B.u[0] = bpack(u0[ks].x, u0[ks].y);
        B.u[1] = bpack(u0[ks].z, u0[ks].w);
        B.u[2] = bpack(u1[ks].x, u1[ks].y);
        B.u[3] = bpack(u1[ks].z, u1[ks].w);
        Bg[ks] = B.s;
    }

    const short* xbh = xb + kh * 256;

    for (int mb = 0; mb < Ne; mb += 32) {
        int arow[2];
#pragma unroll
        for (int i = 0; i < 2; ++i) {
            int s = mb + i * 16 + n;
            arow[i] = toks[s < Ne ? s : Ne - 1] >> 1;
        }
        floatx4 acc[2] = {};
#pragma unroll
        for (int ks = 0; ks < 8; ++ks) {
            const int ko = ks * 32 + quad * 8;
#pragma unroll
            for (int i = 0; i < 2; ++i) {
                const short8 A = *(const short8*)(xbh + (size_t)arow[i] * DDIM + ko);
                acc[i] = __builtin_amdgcn_mfma_f32_16x16x32_bf16(A, Bg[ks], acc[i], 0, 0, 0);
            }
        }
#pragma unroll
        for (int i = 0; i < 2; ++i)
#pragma unroll
            for (int r = 0; r < 4; ++r)
                red[wv][i][r][lane] = acc[i][r];
        __syncthreads();

        {
            const int i = wv & 1;
            const int u = wv >> 1;
#pragma unroll
            for (int rr = 0; rr < 2; ++rr) {
                const int r = u * 2 + rr;
                const int s = mb + i * 16 + quad * 4 + r;
                if (s < Ne) {
                    const int a = toks[s];
                    const float g0 = red[0][i][r][lane] + red[2][i][r][lane];
                    const float g1 = red[1][i][r][lane] + red[3][i][r][lane];
                    const float uu = 0.7978845608f * (g0 + 0.044715f * g0 * g0 * g0);
                    const float sg = 1.0f / (1.0f + __expf(-2.0f * uu));
                    const float v = g0 * sg * g1;
                    act[(size_t)a * HDIM + h0 + n] = (short)(bpack(v, 0.f) & 0xFFFFu);
                }
            }
        }
        __syncthreads();
    }
}

__global__ __launch_bounds__(256, 4) void linear_kernel(
    const short* __restrict__ act, const float* __restrict__ Wl,
    const int* __restrict__ easgn, const float* __restrict__ wts,
    float* __restrict__ out)
{
    const int e  = blockIdx.y;
    const int d0 = blockIdx.x * 16;
    const int tid = threadIdx.x;
    const int wv   = tid >> 6;
    const int lane = tid & 63;
    const int n    = lane & 15;
    const int quad = lane >> 4;

    __shared__ float red[4][2][4][64];
    __shared__ int   toks[LTOK];
    __shared__ float wsl[LTOK];
    __shared__ int   lcnt;

    const int4 eg = ((const int4*)easgn)[tid];
    const float4 wt4 = ((const float4*)wts)[tid];

    const float* Wbase = Wl + ((size_t)e * HDIM + wv * 128 + quad * 8) * DDIM + d0 + n;
    float w[32];
#pragma unroll
    for (int ks = 0; ks < 4; ++ks)
#pragma unroll
        for (int j = 0; j < 8; ++j)
            w[ks * 8 + j] = Wbase[(size_t)(ks * 32 + j) * DDIM];

    if (tid == 0) lcnt = 0;
    RAW_BARRIER();
    if (eg.x == e) { int p = atomicAdd(&lcnt, 1); toks[p] = 4 * tid;     wsl[p] = wt4.x; }
    if (eg.y == e) { int p = atomicAdd(&lcnt, 1); toks[p] = 4 * tid + 1; wsl[p] = wt4.y; }
    if (eg.z == e) { int p = atomicAdd(&lcnt, 1); toks[p] = 4 * tid + 2; wsl[p] = wt4.z; }
    if (eg.w == e) { int p = atomicAdd(&lcnt, 1); toks[p] = 4 * tid + 3; wsl[p] = wt4.w; }
    RAW_BARRIER();
    const int Ne = lcnt;
    if (Ne == 0) return;

    short8 Bl[4];
#pragma unroll
    for (int ks = 0; ks < 4; ++ks) {
        union { short8 s; unsigned u[4]; } B;
        B.u[0] = bpack(w[ks * 8 + 0], w[ks * 8 + 1]);
        B.u[1] = bpack(w[ks * 8 + 2], w[ks * 8 + 3]);
        B.u[2] = bpack(w[ks * 8 + 4], w[ks * 8 + 5]);
        B.u[3] = bpack(w[ks * 8 + 6], w[ks * 8 + 7]);
        Bl[ks] = B.s;
    }

    for (int mb = 0; mb < Ne; mb += 32) {
        int arow[2];
#pragma unroll
        for (int i = 0; i < 2; ++i) {
            int s = mb + i * 16 + n;
            arow[i] = toks[s < Ne ? s : Ne - 1];
        }
        floatx4 acc[2] = {};
#pragma unroll
        for (int ks = 0; ks < 4; ++ks) {
            const int ko = wv * 128 + ks * 32 + quad * 8;
#pragma unroll
            for (int i = 0; i < 2; ++i) {
                const short8 A = *(const short8*)(act + (size_t)arow[i] * HDIM + ko);
                acc[i] = __builtin_amdgcn_mfma_f32_16x16x32_bf16(A, Bl[ks], acc[i], 0, 0, 0);
            }
        }
#pragma unroll
        for (int i = 0; i < 2; ++i)
#pragma unroll
            for (int r = 0; r < 4; ++r)
                red[wv][i][r][lane] = acc[i][r];
        __syncthreads();

        {
            const int i = wv & 1;
            const int u = wv >> 1;
#pragma unroll
            for (int rr = 0; rr < 2; ++rr) {
                const int r = u * 2 + rr;
                const int s = mb + i * 16 + quad * 4 + r;
                if (s < Ne) {
                    const int slot = toks[s];
                    const float v = ((red[0][i][r][lane] + red[1][i][r][lane]) +
                                     (red[2][i][r][lane] + red[3][i][r][lane])) * wsl[s];
                    atomicAdd(&out[(size_t)(slot >> 1) * DDIM + d0 + n], v);
                }
            }
        }
        __syncthreads();
    }
}

extern "C" void kernel_launch(void* const* d_in, const int* in_sizes, int n_in,
                              void* d_out, int out_size, void* d_ws, size_t ws_size,
                              hipStream_t stream)
{
    const float* x   = (const float*)d_in[0];
    const float* rs  = (const float*)d_in[1];
    const float* Wr  = (const float*)d_in[2];
    const float* G   = (const float*)d_in[3];
    const float* Wl  = (const float*)d_in[4];
    const float* pes = (const float*)d_in[5];
    float* out = (float*)d_out;

    char* ws = (char*)d_ws;
    int*   easgn = (int*)(ws);
    float* wts   = (float*)(ws + 4096);
    short* xb    = (short*)(ws + 8192);
    short* act   = (short*)(ws + 532480);

    void* args[] = {
        (void*)&x, (void*)&rs, (void*)&Wr, (void*)&pes, (void*)&G, (void*)&Wl,
        (void*)&easgn, (void*)&wts, (void*)&xb, (void*)&act, (void*)&out
    };
    hipError_t err = hipLaunchCooperativeKernel(
        (const void*)moe_fused, dim3(1024), dim3(256), args, 0, stream);

    if (err != hipSuccess) {
        // fallback: proven 3-kernel pipeline
        router_kernel<<<dim3(LTOK), dim3(256), 0, stream>>>(x, rs, Wr, pes, easgn, wts, xb, out);
        gates_kernel<<<dim3(32, NEXP), dim3(256), 0, stream>>>(xb, G, easgn, act);
        linear_kernel<<<dim3(32, NEXP), dim3(256), 0, stream>>>(act, Wl, easgn, wts, out);
    }
}

// Round 4
// 374.537 us; speedup vs baseline: 1.0832x; 1.0832x over previous
//
#include <hip/hip_runtime.h>
#include <hip/hip_bf16.h>
#include <math.h>

#define LTOK 512
#define DDIM 512
#define NEXP 32
#define HDIM 512

typedef __attribute__((ext_vector_type(8))) short short8;
typedef __attribute__((ext_vector_type(4))) float floatx4;

// round-to-nearest-even fp32->bf16, packed pair: low16 = rne(a), high16 = rne(b)
__device__ __forceinline__ unsigned bpack(float a, float b) {
    unsigned ua = __float_as_uint(a), ub = __float_as_uint(b);
    ua += 0x7FFFu + ((ua >> 16) & 1u);
    ub += 0x7FFFu + ((ub >> 16) & 1u);
    return (ua >> 16) | (ub & 0xFFFF0000u);
}

// Raw barrier WITHOUT the compiler's s_waitcnt vmcnt(0) drain (so in-flight
// weight loads stay in flight across it). Own-wave LDS ops drained.
#define RAW_BARRIER() do { \
    asm volatile("s_waitcnt lgkmcnt(0)" ::: "memory"); \
    __builtin_amdgcn_s_barrier(); \
} while (0)

// ws layout (bytes):
//   [0, 4K)        easgn: int[1024]   easgn[2t+k] = expert of token t's k-th pick
//   [4K, 8K)       wts:   float[1024] = routing weight * per_expert_scale
//   [8K, +512K)    xb:    512x512 bf16 (x rounded to bf16)
//   [532480, +1M)  act:   1024x512 bf16 (slot-indexed activated gate output)
//   [1581056, +128) done: int[32] per-expert arrive counters (router zeroes)

// 256 threads/token-block: 4 waves split the logits K-dim (64 Wr loads/lane).
__global__ __launch_bounds__(256) void router_kernel(
    const float* __restrict__ x, const float* __restrict__ rs,
    const float* __restrict__ Wr, const float* __restrict__ pes,
    int* __restrict__ easgn, float* __restrict__ wts,
    short* __restrict__ xb, float* __restrict__ out,
    int* __restrict__ done)
{
    const int t = blockIdx.x;
    const int tid = threadIdx.x;
    const int lane = tid & 63;
    const int wv = tid >> 6;

    // zero the per-expert arrive counters for the fused expert kernel
    if (t == 0 && tid < NEXP) done[tid] = 0;

    float xv[2];
    float ss = 0.f;
#pragma unroll
    for (int j = 0; j < 2; ++j) {
        xv[j] = x[t * DDIM + j * 256 + tid];
        ss += xv[j] * xv[j];
    }
    // emit bf16 copy of x for the expert GEMMs; zero this token's out row
#pragma unroll
    for (int j = 0; j < 2; ++j) {
        xb[t * DDIM + j * 256 + tid] = (short)(bpack(xv[j], 0.f) & 0xFFFFu);
        out[t * DDIM + j * 256 + tid] = 0.f;
    }

#pragma unroll
    for (int o = 32; o > 0; o >>= 1) ss += __shfl_xor(ss, o);
    __shared__ float sred[4];
    if (lane == 0) sred[wv] = ss;
    __syncthreads();
    ss = (sred[0] + sred[1]) + (sred[2] + sred[3]);
    const float var = ss * (1.0f / 512.0f);
    const float coef = rsqrtf(var + 1e-6f) * rsqrtf(512.0f);

    __shared__ float ri[DDIM];
#pragma unroll
    for (int j = 0; j < 2; ++j) {
        const int d = j * 256 + tid;
        ri[d] = xv[j] * coef * rs[d];
    }
    __syncthreads();

    // logits: tid&31 -> expert, tid>>5 -> 1/8th of D (64 d each)
    const int e = tid & 31;
    const int seg = tid >> 5;
    const int dbeg = seg * 64;
    float l0 = 0.f, l1 = 0.f, l2 = 0.f, l3 = 0.f;
#pragma unroll 4
    for (int d = dbeg; d < dbeg + 64; d += 4) {
        l0 = fmaf(ri[d + 0], Wr[(d + 0) * NEXP + e], l0);
        l1 = fmaf(ri[d + 1], Wr[(d + 1) * NEXP + e], l1);
        l2 = fmaf(ri[d + 2], Wr[(d + 2) * NEXP + e], l2);
        l3 = fmaf(ri[d + 3], Wr[(d + 3) * NEXP + e], l3);
    }
    __shared__ float lpart[8][NEXP];
    lpart[seg][e] = (l0 + l1) + (l2 + l3);
    __syncthreads();

    __shared__ float lgs[NEXP];
    if (tid < NEXP) {
        float v = 0.f;
#pragma unroll
        for (int s = 0; s < 8; ++s) v += lpart[s][tid];
        lgs[tid] = v;
    }
    __syncthreads();

    if (tid == 0) {
        int i0 = 0; float m0 = lgs[0];
        for (int i = 1; i < NEXP; ++i) if (lgs[i] > m0) { m0 = lgs[i]; i0 = i; }
        int i1 = -1; float m1 = -1e30f;
        for (int i = 0; i < NEXP; ++i) if (i != i0 && lgs[i] > m1) { m1 = lgs[i]; i1 = i; }
        // softmax denom cancels against renorm: weights depend only on top-2 logits
        const float e1 = expf(m1 - m0);
        const float inv = 1.0f / (1.0f + e1);
        easgn[2 * t]     = i0;
        easgn[2 * t + 1] = i1;
        wts[2 * t]     = inv * pes[i0];
        wts[2 * t + 1] = e1 * inv * pes[i1];
    }
}

// ============================================================================
// FUSED gates+linear. grid (32, 32): blockIdx.x = tile (h-tile for gates,
// d-tile for linear), blockIdx.y = expert. 1024 blocks = exactly 4/CU x 256 CU
// (launch_bounds(256,4) + 12.3 KB LDS -> co-residency GUARANTEED, so the
// per-expert spin cannot deadlock: every block finishes its gates phase and
// arrives before waiting, and it waits only on its own expert's 32 blocks).
// No cross-phase register residency (the R3 spill bug): G regs die at gates
// pack; Wl regs are issued after the arrive, hiding HBM latency under the spin.
// Scan computed ONCE (toks/wsl/Ne persist in LDS across both phases).
// Cross-block act visibility: writer-side __threadfence (L2 writeback) before
// release-arrive; reader-side agent-scope acquire load per wave (buffer_inv,
// drops stale act lines - per-XCD L2s are not coherent, G16).
// ============================================================================
__global__ __launch_bounds__(256, 4) void expert_kernel(
    const short* __restrict__ xb, const float* __restrict__ G,
    const float* __restrict__ Wl,
    const int* __restrict__ easgn, const float* __restrict__ wts,
    short* __restrict__ act, float* __restrict__ out,
    int* __restrict__ done)
{
    const int e    = blockIdx.y;
    const int tile = blockIdx.x;
    const int h0   = tile * 16;
    const int d0   = tile * 16;
    const int tid  = threadIdx.x;
    const int wv   = tid >> 6;
    const int g    = wv & 1;    // gate index (gates phase)
    const int kh   = wv >> 1;   // K half (gates phase)
    const int lane = tid & 63;
    const int n    = lane & 15;
    const int quad = lane >> 4;

    __shared__ float red[4][2][4][64];   // 8 KB
    __shared__ int   toks[LTOK];         // 2 KB (persists into linear phase)
    __shared__ float wsl[LTOK];          // 2 KB
    __shared__ int   lcnt;

    // easgn/wts loads issued FIRST (oldest vmem slots -> scan waits only on them)
    const int4   eg  = ((const int4*)easgn)[tid];
    const float4 wt4 = ((const float4*)wts)[tid];

    // ---- G register stage: 16 x global_load_dwordx4 per lane ----
    const float* Gl = G + ((size_t)((e * 2 + g) * HDIM) + h0 + n) * DDIM + kh * 256 + quad * 8;
    floatx4 u0[8], u1[8];
#pragma unroll
    for (int ks = 0; ks < 8; ++ks) {
        u0[ks] = *(const floatx4*)(Gl + ks * 32);
        u1[ks] = *(const floatx4*)(Gl + ks * 32 + 4);
    }

    // ---- self-select scan (once; reused by linear), under the G flight ----
    if (tid == 0) lcnt = 0;
    RAW_BARRIER();
    if (eg.x == e) { int p = atomicAdd(&lcnt, 1); toks[p] = 4 * tid;     wsl[p] = wt4.x; }
    if (eg.y == e) { int p = atomicAdd(&lcnt, 1); toks[p] = 4 * tid + 1; wsl[p] = wt4.y; }
    if (eg.z == e) { int p = atomicAdd(&lcnt, 1); toks[p] = 4 * tid + 2; wsl[p] = wt4.z; }
    if (eg.w == e) { int p = atomicAdd(&lcnt, 1); toks[p] = 4 * tid + 3; wsl[p] = wt4.w; }
    RAW_BARRIER();
    const int Ne = lcnt;

    // ---- pack gates B fragments (G regs die here) ----
    short8 Bg[8];
#pragma unroll
    for (int ks = 0; ks < 8; ++ks) {
        union { short8 s; unsigned u[4]; } B;
        B.u[0] = bpack(u0[ks].x, u0[ks].y);
        B.u[1] = bpack(u0[ks].z, u0[ks].w);
        B.u[2] = bpack(u1[ks].x, u1[ks].y);
        B.u[3] = bpack(u1[ks].z, u1[ks].w);
        Bg[ks] = B.s;
    }

    // ================= gates phase =================
    if (Ne > 0) {
        const short* xbh = xb + kh * 256;
        for (int mb = 0; mb < Ne; mb += 32) {
            int arow[2];
#pragma unroll
            for (int i = 0; i < 2; ++i) {
                int s = mb + i * 16 + n;
                arow[i] = toks[s < Ne ? s : Ne - 1] >> 1;   // token index
            }
            floatx4 acc[2] = {};
#pragma unroll
            for (int ks = 0; ks < 8; ++ks) {
                const int ko = ks * 32 + quad * 8;
#pragma unroll
                for (int i = 0; i < 2; ++i) {
                    const short8 A = *(const short8*)(xbh + (size_t)arow[i] * DDIM + ko);
                    acc[i] = __builtin_amdgcn_mfma_f32_16x16x32_bf16(A, Bg[ks], acc[i], 0, 0, 0);
                }
            }
#pragma unroll
            for (int i = 0; i < 2; ++i)
#pragma unroll
                for (int r = 0; r < 4; ++r)
                    red[wv][i][r][lane] = acc[i][r];
            __syncthreads();

            // epilogue: wave handles m-tile (wv&1), regs {2u,2u+1}, u=wv>>1.
            {
                const int i = wv & 1;
                const int u = wv >> 1;
#pragma unroll
                for (int rr = 0; rr < 2; ++rr) {
                    const int r = u * 2 + rr;
                    const int s = mb + i * 16 + quad * 4 + r;
                    if (s < Ne) {
                        const int a = toks[s];   // slot id = act row
                        const float g0 = red[0][i][r][lane] + red[2][i][r][lane];
                        const float g1 = red[1][i][r][lane] + red[3][i][r][lane];
                        const float uu = 0.7978845608f * (g0 + 0.044715f * g0 * g0 * g0);
                        const float sg = 1.0f / (1.0f + __expf(-2.0f * uu));
                        const float v = g0 * sg * g1;
                        act[(size_t)a * HDIM + h0 + n] = (short)(bpack(v, 0.f) & 0xFFFFu);
                    }
                }
            }
            __syncthreads();
        }
    }

    // ---- release: make act stores visible, then arrive on done[e] ----
    __threadfence();          // per-wave vmcnt drain + L2 writeback
    __syncthreads();          // all waves' fences done before the arrive
    if (tid == 0)
        __hip_atomic_fetch_add(&done[e], 1, __ATOMIC_RELEASE, __HIP_MEMORY_SCOPE_AGENT);

    if (Ne == 0) return;      // nothing to do in linear; slot frees up

    // ---- Wl register stage issued BEFORE the spin (latency hides under it) ----
    const float* Wbase = Wl + ((size_t)e * HDIM + wv * 128 + quad * 8) * DDIM + d0 + n;
    float w[32];
#pragma unroll
    for (int ks = 0; ks < 4; ++ks)
#pragma unroll
        for (int j = 0; j < 8; ++j)
            w[ks * 8 + j] = Wbase[(size_t)(ks * 32 + j) * DDIM];

    // ---- acquire: wait for all 32 gates blocks of this expert ----
    if (tid == 0) {
        while (__hip_atomic_load(&done[e], __ATOMIC_ACQUIRE, __HIP_MEMORY_SCOPE_AGENT) < NEXP)
            __builtin_amdgcn_s_sleep(8);
    }
    __syncthreads();
    // per-wave acquire (buffer_inv): drop stale act lines before reading them
    (void)__hip_atomic_load(&done[e], __ATOMIC_ACQUIRE, __HIP_MEMORY_SCOPE_AGENT);

    // ---- pack linear B fragments ----
    short8 Bl[4];
#pragma unroll
    for (int ks = 0; ks < 4; ++ks) {
        union { short8 s; unsigned u[4]; } B;
        B.u[0] = bpack(w[ks * 8 + 0], w[ks * 8 + 1]);
        B.u[1] = bpack(w[ks * 8 + 2], w[ks * 8 + 3]);
        B.u[2] = bpack(w[ks * 8 + 4], w[ks * 8 + 5]);
        B.u[3] = bpack(w[ks * 8 + 6], w[ks * 8 + 7]);
        Bl[ks] = B.s;
    }

    // ================= linear phase (toks/wsl/Ne reused) =================
    for (int mb = 0; mb < Ne; mb += 32) {
        int arow[2];
#pragma unroll
        for (int i = 0; i < 2; ++i) {
            int s = mb + i * 16 + n;
            arow[i] = toks[s < Ne ? s : Ne - 1];   // slot id = act row
        }
        floatx4 acc[2] = {};
#pragma unroll
        for (int ks = 0; ks < 4; ++ks) {
            const int ko = wv * 128 + ks * 32 + quad * 8;
#pragma unroll
            for (int i = 0; i < 2; ++i) {
                const short8 A = *(const short8*)(act + (size_t)arow[i] * HDIM + ko);
                acc[i] = __builtin_amdgcn_mfma_f32_16x16x32_bf16(A, Bl[ks], acc[i], 0, 0, 0);
            }
        }
#pragma unroll
        for (int i = 0; i < 2; ++i)
#pragma unroll
            for (int r = 0; r < 4; ++r)
                red[wv][i][r][lane] = acc[i][r];
        __syncthreads();

        {
            const int i = wv & 1;
            const int u = wv >> 1;
#pragma unroll
            for (int rr = 0; rr < 2; ++rr) {
                const int r = u * 2 + rr;
                const int s = mb + i * 16 + quad * 4 + r;
                if (s < Ne) {
                    const int slot = toks[s];
                    const float v = ((red[0][i][r][lane] + red[1][i][r][lane]) +
                                     (red[2][i][r][lane] + red[3][i][r][lane])) * wsl[s];
                    atomicAdd(&out[(size_t)(slot >> 1) * DDIM + d0 + n], v);
                }
            }
        }
        __syncthreads();
    }
}

extern "C" void kernel_launch(void* const* d_in, const int* in_sizes, int n_in,
                              void* d_out, int out_size, void* d_ws, size_t ws_size,
                              hipStream_t stream)
{
    const float* x   = (const float*)d_in[0];
    const float* rs  = (const float*)d_in[1];
    const float* Wr  = (const float*)d_in[2];
    const float* G   = (const float*)d_in[3];
    const float* Wl  = (const float*)d_in[4];
    const float* pes = (const float*)d_in[5];
    float* out = (float*)d_out;

    char* ws = (char*)d_ws;
    int*   easgn = (int*)(ws);
    float* wts   = (float*)(ws + 4096);
    short* xb    = (short*)(ws + 8192);
    short* act   = (short*)(ws + 532480);
    int*   done  = (int*)(ws + 1581056);

    router_kernel<<<dim3(LTOK), dim3(256), 0, stream>>>(x, rs, Wr, pes, easgn, wts, xb, out, done);
    expert_kernel<<<dim3(32, NEXP), dim3(256), 0, stream>>>(xb, G, Wl, easgn, wts, act, out, done);
}

// Round 5
// 238.575 us; speedup vs baseline: 1.7006x; 1.5699x over previous
//
#include <hip/hip_runtime.h>
#include <hip/hip_bf16.h>
#include <math.h>

#define LTOK 512
#define DDIM 512
#define NEXP 32
#define HDIM 512

typedef __attribute__((ext_vector_type(8))) short short8;
typedef __attribute__((ext_vector_type(4))) float floatx4;

// round-to-nearest-even fp32->bf16, packed pair: low16 = rne(a), high16 = rne(b)
__device__ __forceinline__ unsigned bpack(float a, float b) {
    unsigned ua = __float_as_uint(a), ub = __float_as_uint(b);
    ua += 0x7FFFu + ((ua >> 16) & 1u);
    ub += 0x7FFFu + ((ub >> 16) & 1u);
    return (ua >> 16) | (ub & 0xFFFF0000u);
}

// Raw barrier WITHOUT the compiler's s_waitcnt vmcnt(0) drain (so in-flight
// weight loads stay in flight across it). Own-wave LDS ops drained.
#define RAW_BARRIER() do { \
    asm volatile("s_waitcnt lgkmcnt(0)" ::: "memory"); \
    __builtin_amdgcn_s_barrier(); \
} while (0)

// ws layout (bytes):
//   [0, 4K)        easgn: int[1024]   easgn[2t+k] = expert of token t's k-th pick
//   [4K, 8K)       wts:   float[1024] = routing weight * per_expert_scale
//   [8K, +512K)    xb:    512x512 bf16 (x rounded to bf16)
//   [532480, +1M)  act:   1024x512 bf16 (slot-indexed activated gate output)
//   [1581056, +128) done: int[32] per-expert arrive counters (router zeroes)

// 256 threads/token-block: 4 waves split the logits K-dim (64 Wr loads/lane).
__global__ __launch_bounds__(256) void router_kernel(
    const float* __restrict__ x, const float* __restrict__ rs,
    const float* __restrict__ Wr, const float* __restrict__ pes,
    int* __restrict__ easgn, float* __restrict__ wts,
    short* __restrict__ xb, float* __restrict__ out,
    int* __restrict__ done)
{
    const int t = blockIdx.x;
    const int tid = threadIdx.x;
    const int lane = tid & 63;
    const int wv = tid >> 6;

    // zero the per-expert arrive counters for the fused expert kernel
    if (t == 0 && tid < NEXP) done[tid] = 0;

    float xv[2];
    float ss = 0.f;
#pragma unroll
    for (int j = 0; j < 2; ++j) {
        xv[j] = x[t * DDIM + j * 256 + tid];
        ss += xv[j] * xv[j];
    }
    // emit bf16 copy of x for the expert GEMMs; zero this token's out row
#pragma unroll
    for (int j = 0; j < 2; ++j) {
        xb[t * DDIM + j * 256 + tid] = (short)(bpack(xv[j], 0.f) & 0xFFFFu);
        out[t * DDIM + j * 256 + tid] = 0.f;
    }

#pragma unroll
    for (int o = 32; o > 0; o >>= 1) ss += __shfl_xor(ss, o);
    __shared__ float sred[4];
    if (lane == 0) sred[wv] = ss;
    __syncthreads();
    ss = (sred[0] + sred[1]) + (sred[2] + sred[3]);
    const float var = ss * (1.0f / 512.0f);
    const float coef = rsqrtf(var + 1e-6f) * rsqrtf(512.0f);

    __shared__ float ri[DDIM];
#pragma unroll
    for (int j = 0; j < 2; ++j) {
        const int d = j * 256 + tid;
        ri[d] = xv[j] * coef * rs[d];
    }
    __syncthreads();

    // logits: tid&31 -> expert, tid>>5 -> 1/8th of D (64 d each)
    const int e = tid & 31;
    const int seg = tid >> 5;
    const int dbeg = seg * 64;
    float l0 = 0.f, l1 = 0.f, l2 = 0.f, l3 = 0.f;
#pragma unroll 4
    for (int d = dbeg; d < dbeg + 64; d += 4) {
        l0 = fmaf(ri[d + 0], Wr[(d + 0) * NEXP + e], l0);
        l1 = fmaf(ri[d + 1], Wr[(d + 1) * NEXP + e], l1);
        l2 = fmaf(ri[d + 2], Wr[(d + 2) * NEXP + e], l2);
        l3 = fmaf(ri[d + 3], Wr[(d + 3) * NEXP + e], l3);
    }
    __shared__ float lpart[8][NEXP];
    lpart[seg][e] = (l0 + l1) + (l2 + l3);
    __syncthreads();

    __shared__ float lgs[NEXP];
    if (tid < NEXP) {
        float v = 0.f;
#pragma unroll
        for (int s = 0; s < 8; ++s) v += lpart[s][tid];
        lgs[tid] = v;
    }
    __syncthreads();

    if (tid == 0) {
        int i0 = 0; float m0 = lgs[0];
        for (int i = 1; i < NEXP; ++i) if (lgs[i] > m0) { m0 = lgs[i]; i0 = i; }
        int i1 = -1; float m1 = -1e30f;
        for (int i = 0; i < NEXP; ++i) if (i != i0 && lgs[i] > m1) { m1 = lgs[i]; i1 = i; }
        // softmax denom cancels against renorm: weights depend only on top-2 logits
        const float e1 = expf(m1 - m0);
        const float inv = 1.0f / (1.0f + e1);
        easgn[2 * t]     = i0;
        easgn[2 * t + 1] = i1;
        wts[2 * t]     = inv * pes[i0];
        wts[2 * t + 1] = e1 * inv * pes[i1];
    }
}

// ============================================================================
// FUSED gates+linear. grid (32, 32): blockIdx.x = tile (h-tile for gates,
// d-tile for linear), blockIdx.y = expert. 1024 blocks = exactly 4/CU x 256 CU
// (launch_bounds(256,4) + 12.8 KB LDS + 44 VGPR -> co-residency GUARANTEED,
// so the per-expert wait cannot deadlock).
// R5 sync fix (the R4 killer was ~10^6 L2 invalidates from acquire-in-spin):
//   release: __syncthreads (vmcnt drain -> act stores in L2) + tid0-only
//            fetch_add RELEASE/AGENT (one buffer_wbl2 + MALL atomic per block).
//   wait:    tid0 spins on RELAXED/AGENT loads (sc1 read from MALL, NO
//            buffer_inv), then ONE acquire fence per block after the spin
//            exits (single buffer_inv; G/Wl already in registers, act must be
//            refetched anyway -> the inv is nearly free).
// Scan computed ONCE (toks/wsl/Ne persist in LDS across both phases).
// Wl register stage issued BEFORE the wait so its HBM latency hides under it.
// ============================================================================
__global__ __launch_bounds__(256, 4) void expert_kernel(
    const short* __restrict__ xb, const float* __restrict__ G,
    const float* __restrict__ Wl,
    const int* __restrict__ easgn, const float* __restrict__ wts,
    short* __restrict__ act, float* __restrict__ out,
    int* __restrict__ done)
{
    const int e    = blockIdx.y;
    const int tile = blockIdx.x;
    const int h0   = tile * 16;
    const int d0   = tile * 16;
    const int tid  = threadIdx.x;
    const int wv   = tid >> 6;
    const int g    = wv & 1;    // gate index (gates phase)
    const int kh   = wv >> 1;   // K half (gates phase)
    const int lane = tid & 63;
    const int n    = lane & 15;
    const int quad = lane >> 4;

    __shared__ float red[4][2][4][64];   // 8 KB
    __shared__ int   toks[LTOK];         // 2 KB (persists into linear phase)
    __shared__ float wsl[LTOK];          // 2 KB
    __shared__ int   lcnt;

    // easgn/wts loads issued FIRST (oldest vmem slots -> scan waits only on them)
    const int4   eg  = ((const int4*)easgn)[tid];
    const float4 wt4 = ((const float4*)wts)[tid];

    // ---- G register stage: 16 x global_load_dwordx4 per lane ----
    const float* Gl = G + ((size_t)((e * 2 + g) * HDIM) + h0 + n) * DDIM + kh * 256 + quad * 8;
    floatx4 u0[8], u1[8];
#pragma unroll
    for (int ks = 0; ks < 8; ++ks) {
        u0[ks] = *(const floatx4*)(Gl + ks * 32);
        u1[ks] = *(const floatx4*)(Gl + ks * 32 + 4);
    }

    // ---- self-select scan (once; reused by linear), under the G flight ----
    if (tid == 0) lcnt = 0;
    RAW_BARRIER();
    if (eg.x == e) { int p = atomicAdd(&lcnt, 1); toks[p] = 4 * tid;     wsl[p] = wt4.x; }
    if (eg.y == e) { int p = atomicAdd(&lcnt, 1); toks[p] = 4 * tid + 1; wsl[p] = wt4.y; }
    if (eg.z == e) { int p = atomicAdd(&lcnt, 1); toks[p] = 4 * tid + 2; wsl[p] = wt4.z; }
    if (eg.w == e) { int p = atomicAdd(&lcnt, 1); toks[p] = 4 * tid + 3; wsl[p] = wt4.w; }
    RAW_BARRIER();
    const int Ne = lcnt;

    // ---- pack gates B fragments (G regs die here) ----
    short8 Bg[8];
#pragma unroll
    for (int ks = 0; ks < 8; ++ks) {
        union { short8 s; unsigned u[4]; } B;
        B.u[0] = bpack(u0[ks].x, u0[ks].y);
        B.u[1] = bpack(u0[ks].z, u0[ks].w);
        B.u[2] = bpack(u1[ks].x, u1[ks].y);
        B.u[3] = bpack(u1[ks].z, u1[ks].w);
        Bg[ks] = B.s;
    }

    // ================= gates phase =================
    if (Ne > 0) {
        const short* xbh = xb + kh * 256;
        for (int mb = 0; mb < Ne; mb += 32) {
            int arow[2];
#pragma unroll
            for (int i = 0; i < 2; ++i) {
                int s = mb + i * 16 + n;
                arow[i] = toks[s < Ne ? s : Ne - 1] >> 1;   // token index
            }
            floatx4 acc[2] = {};
#pragma unroll
            for (int ks = 0; ks < 8; ++ks) {
                const int ko = ks * 32 + quad * 8;
#pragma unroll
                for (int i = 0; i < 2; ++i) {
                    const short8 A = *(const short8*)(xbh + (size_t)arow[i] * DDIM + ko);
                    acc[i] = __builtin_amdgcn_mfma_f32_16x16x32_bf16(A, Bg[ks], acc[i], 0, 0, 0);
                }
            }
#pragma unroll
            for (int i = 0; i < 2; ++i)
#pragma unroll
                for (int r = 0; r < 4; ++r)
                    red[wv][i][r][lane] = acc[i][r];
            __syncthreads();

            // epilogue: wave handles m-tile (wv&1), regs {2u,2u+1}, u=wv>>1.
            {
                const int i = wv & 1;
                const int u = wv >> 1;
#pragma unroll
                for (int rr = 0; rr < 2; ++rr) {
                    const int r = u * 2 + rr;
                    const int s = mb + i * 16 + quad * 4 + r;
                    if (s < Ne) {
                        const int a = toks[s];   // slot id = act row
                        const float g0 = red[0][i][r][lane] + red[2][i][r][lane];
                        const float g1 = red[1][i][r][lane] + red[3][i][r][lane];
                        const float uu = 0.7978845608f * (g0 + 0.044715f * g0 * g0 * g0);
                        const float sg = 1.0f / (1.0f + __expf(-2.0f * uu));
                        const float v = g0 * sg * g1;
                        act[(size_t)a * HDIM + h0 + n] = (short)(bpack(v, 0.f) & 0xFFFFu);
                    }
                }
            }
            __syncthreads();
        }
    }

    // ---- release: drain own act stores to L2, then one wbl2+atomic (tid0) ----
    __syncthreads();   // per-wave s_waitcnt vmcnt(0) before barrier: stores in L2
    if (tid == 0)
        __hip_atomic_fetch_add(&done[e], 1, __ATOMIC_RELEASE, __HIP_MEMORY_SCOPE_AGENT);

    if (Ne == 0) return;      // arrived already; nothing to do in linear

    // ---- Wl register stage issued BEFORE the wait (latency hides under it) ----
    const float* Wbase = Wl + ((size_t)e * HDIM + wv * 128 + quad * 8) * DDIM + d0 + n;
    float w[32];
#pragma unroll
    for (int ks = 0; ks < 4; ++ks)
#pragma unroll
        for (int j = 0; j < 8; ++j)
            w[ks * 8 + j] = Wbase[(size_t)(ks * 32 + j) * DDIM];

    // ---- wait: RELAXED spin (no L2 invalidate), then ONE acquire fence ----
    if (tid == 0) {
        while (__hip_atomic_load(&done[e], __ATOMIC_RELAXED, __HIP_MEMORY_SCOPE_AGENT) < NEXP)
            __builtin_amdgcn_s_sleep(8);
    }
    __syncthreads();
    __builtin_amdgcn_fence(__ATOMIC_ACQUIRE, "agent");   // single buffer_inv/block

    // ---- pack linear B fragments ----
    short8 Bl[4];
#pragma unroll
    for (int ks = 0; ks < 4; ++ks) {
        union { short8 s; unsigned u[4]; } B;
        B.u[0] = bpack(w[ks * 8 + 0], w[ks * 8 + 1]);
        B.u[1] = bpack(w[ks * 8 + 2], w[ks * 8 + 3]);
        B.u[2] = bpack(w[ks * 8 + 4], w[ks * 8 + 5]);
        B.u[3] = bpack(w[ks * 8 + 6], w[ks * 8 + 7]);
        Bl[ks] = B.s;
    }

    // ================= linear phase (toks/wsl/Ne reused) =================
    for (int mb = 0; mb < Ne; mb += 32) {
        int arow[2];
#pragma unroll
        for (int i = 0; i < 2; ++i) {
            int s = mb + i * 16 + n;
            arow[i] = toks[s < Ne ? s : Ne - 1];   // slot id = act row
        }
        floatx4 acc[2] = {};
#pragma unroll
        for (int ks = 0; ks < 4; ++ks) {
            const int ko = wv * 128 + ks * 32 + quad * 8;
#pragma unroll
            for (int i = 0; i < 2; ++i) {
                const short8 A = *(const short8*)(act + (size_t)arow[i] * HDIM + ko);
                acc[i] = __builtin_amdgcn_mfma_f32_16x16x32_bf16(A, Bl[ks], acc[i], 0, 0, 0);
            }
        }
#pragma unroll
        for (int i = 0; i < 2; ++i)
#pragma unroll
            for (int r = 0; r < 4; ++r)
                red[wv][i][r][lane] = acc[i][r];
        __syncthreads();

        {
            const int i = wv & 1;
            const int u = wv >> 1;
#pragma unroll
            for (int rr = 0; rr < 2; ++rr) {
                const int r = u * 2 + rr;
                const int s = mb + i * 16 + quad * 4 + r;
                if (s < Ne) {
                    const int slot = toks[s];
                    const float v = ((red[0][i][r][lane] + red[1][i][r][lane]) +
                                     (red[2][i][r][lane] + red[3][i][r][lane])) * wsl[s];
                    atomicAdd(&out[(size_t)(slot >> 1) * DDIM + d0 + n], v);
                }
            }
        }
        __syncthreads();
    }
}

extern "C" void kernel_launch(void* const* d_in, const int* in_sizes, int n_in,
                              void* d_out, int out_size, void* d_ws, size_t ws_size,
                              hipStream_t stream)
{
    const float* x   = (const float*)d_in[0];
    const float* rs  = (const float*)d_in[1];
    const float* Wr  = (const float*)d_in[2];
    const float* G   = (const float*)d_in[3];
    const float* Wl  = (const float*)d_in[4];
    const float* pes = (const float*)d_in[5];
    float* out = (float*)d_out;

    char* ws = (char*)d_ws;
    int*   easgn = (int*)(ws);
    float* wts   = (float*)(ws + 4096);
    short* xb    = (short*)(ws + 8192);
    short* act   = (short*)(ws + 532480);
    int*   done  = (int*)(ws + 1581056);

    router_kernel<<<dim3(LTOK), dim3(256), 0, stream>>>(x, rs, Wr, pes, easgn, wts, xb, out, done);
    expert_kernel<<<dim3(32, NEXP), dim3(256), 0, stream>>>(xb, G, Wl, easgn, wts, act, out, done);
}

// Round 6
// 198.213 us; speedup vs baseline: 2.0469x; 1.2036x over previous
//
#include <hip/hip_runtime.h>
#include <hip/hip_bf16.h>
#include <math.h>

#define LTOK 512
#define DDIM 512
#define NEXP 32
#define HDIM 512

typedef __attribute__((ext_vector_type(8))) short short8;
typedef __attribute__((ext_vector_type(4))) float floatx4;

// round-to-nearest-even fp32->bf16, packed pair: low16 = rne(a), high16 = rne(b)
__device__ __forceinline__ unsigned bpack(float a, float b) {
    unsigned ua = __float_as_uint(a), ub = __float_as_uint(b);
    ua += 0x7FFFu + ((ua >> 16) & 1u);
    ub += 0x7FFFu + ((ub >> 16) & 1u);
    return (ua >> 16) | (ub & 0xFFFF0000u);
}

// Raw barrier WITHOUT the compiler's s_waitcnt vmcnt(0) drain (so in-flight
// weight loads stay in flight across it). Own-wave LDS ops drained.
#define RAW_BARRIER() do { \
    asm volatile("s_waitcnt lgkmcnt(0)" ::: "memory"); \
    __builtin_amdgcn_s_barrier(); \
} while (0)

// MALL-coherent accessors: sc0 sc1 bypass L1+L2 both ways, so cross-block
// act traffic needs NO buffer_wbl2 / buffer_inv sweeps (the R5 killer:
// 1024 per-block L2 maintenance ops serialize at the 8 L2s ~= 100 us).
__device__ __forceinline__ floatx4 mall_load_b128(const void* p) {
    floatx4 r;
    asm volatile("global_load_dwordx4 %0, %1, off sc0 sc1" : "=v"(r) : "v"(p));
    return r;
}
__device__ __forceinline__ void mall_store_b16(void* p, unsigned v16) {
    asm volatile("global_store_short %0, %1, off sc0 sc1"
                 :: "v"(p), "v"(v16) : "memory");
}

// ws layout (bytes):
//   [0, 4K)        easgn: int[1024]   easgn[2t+k] = expert of token t's k-th pick
//   [4K, 8K)       wts:   float[1024] = routing weight * per_expert_scale
//   [8K, +512K)    xb:    512x512 bf16 (x rounded to bf16)
//   [532480, +1M)  act:   1024x512 bf16 (slot-indexed activated gate output)
//   [1581056, +128) done: int[32] per-expert arrive counters (router zeroes)

// 256 threads/token-block: 4 waves split the logits K-dim (64 Wr loads/lane).
__global__ __launch_bounds__(256) void router_kernel(
    const float* __restrict__ x, const float* __restrict__ rs,
    const float* __restrict__ Wr, const float* __restrict__ pes,
    int* __restrict__ easgn, float* __restrict__ wts,
    short* __restrict__ xb, float* __restrict__ out,
    int* __restrict__ done)
{
    const int t = blockIdx.x;
    const int tid = threadIdx.x;
    const int lane = tid & 63;
    const int wv = tid >> 6;

    // zero the per-expert arrive counters for the fused expert kernel
    // (kernel-end L2 flush makes this visible to the expert kernel's
    //  MALL-level atomics)
    if (t == 0 && tid < NEXP) done[tid] = 0;

    float xv[2];
    float ss = 0.f;
#pragma unroll
    for (int j = 0; j < 2; ++j) {
        xv[j] = x[t * DDIM + j * 256 + tid];
        ss += xv[j] * xv[j];
    }
    // emit bf16 copy of x for the expert GEMMs; zero this token's out row
#pragma unroll
    for (int j = 0; j < 2; ++j) {
        xb[t * DDIM + j * 256 + tid] = (short)(bpack(xv[j], 0.f) & 0xFFFFu);
        out[t * DDIM + j * 256 + tid] = 0.f;
    }

#pragma unroll
    for (int o = 32; o > 0; o >>= 1) ss += __shfl_xor(ss, o);
    __shared__ float sred[4];
    if (lane == 0) sred[wv] = ss;
    __syncthreads();
    ss = (sred[0] + sred[1]) + (sred[2] + sred[3]);
    const float var = ss * (1.0f / 512.0f);
    const float coef = rsqrtf(var + 1e-6f) * rsqrtf(512.0f);

    __shared__ float ri[DDIM];
#pragma unroll
    for (int j = 0; j < 2; ++j) {
        const int d = j * 256 + tid;
        ri[d] = xv[j] * coef * rs[d];
    }
    __syncthreads();

    // logits: tid&31 -> expert, tid>>5 -> 1/8th of D (64 d each)
    const int e = tid & 31;
    const int seg = tid >> 5;
    const int dbeg = seg * 64;
    float l0 = 0.f, l1 = 0.f, l2 = 0.f, l3 = 0.f;
#pragma unroll 4
    for (int d = dbeg; d < dbeg + 64; d += 4) {
        l0 = fmaf(ri[d + 0], Wr[(d + 0) * NEXP + e], l0);
        l1 = fmaf(ri[d + 1], Wr[(d + 1) * NEXP + e], l1);
        l2 = fmaf(ri[d + 2], Wr[(d + 2) * NEXP + e], l2);
        l3 = fmaf(ri[d + 3], Wr[(d + 3) * NEXP + e], l3);
    }
    __shared__ float lpart[8][NEXP];
    lpart[seg][e] = (l0 + l1) + (l2 + l3);
    __syncthreads();

    __shared__ float lgs[NEXP];
    if (tid < NEXP) {
        float v = 0.f;
#pragma unroll
        for (int s = 0; s < 8; ++s) v += lpart[s][tid];
        lgs[tid] = v;
    }
    __syncthreads();

    if (tid == 0) {
        int i0 = 0; float m0 = lgs[0];
        for (int i = 1; i < NEXP; ++i) if (lgs[i] > m0) { m0 = lgs[i]; i0 = i; }
        int i1 = -1; float m1 = -1e30f;
        for (int i = 0; i < NEXP; ++i) if (i != i0 && lgs[i] > m1) { m1 = lgs[i]; i1 = i; }
        // softmax denom cancels against renorm: weights depend only on top-2 logits
        const float e1 = expf(m1 - m0);
        const float inv = 1.0f / (1.0f + e1);
        easgn[2 * t]     = i0;
        easgn[2 * t + 1] = i1;
        wts[2 * t]     = inv * pes[i0];
        wts[2 * t + 1] = e1 * inv * pes[i1];
    }
}

// ============================================================================
// FUSED gates+linear. grid (32, 32): blockIdx.x = tile (h-tile for gates,
// d-tile for linear), blockIdx.y = expert. 1024 blocks = exactly 4/CU x 256 CU
// (launch_bounds(256,4) + 12.8 KB LDS + low VGPR -> co-residency GUARANTEED,
// so the per-expert wait cannot deadlock).
// R6 sync: ZERO cache-maintenance ops.
//   - act is the ONLY cross-block data inside this kernel. Gates write it
//     with sc0 sc1 write-through stores (land at MALL); linear reads it with
//     sc0 sc1 loads (read MALL; stale L1/L2 irrelevant). Everything else
//     (xb/G/Wl/easgn/wts) is covered by kernel-boundary coherence and stays
//     normally cached.
//   - release: s_waitcnt vmcnt(0) (stores at MALL) + barrier + tid0 RELAXED
//     agent fetch_add (single MALL atomic; NO buffer_wbl2).
//   - wait: tid0 RELAXED agent spin + barrier (NO buffer_inv).
// Scan computed ONCE (toks/wsl/Ne persist in LDS across both phases).
// Wl register stage issued BEFORE the wait so its HBM latency hides under it.
// ============================================================================
__global__ __launch_bounds__(256, 4) void expert_kernel(
    const short* __restrict__ xb, const float* __restrict__ G,
    const float* __restrict__ Wl,
    const int* __restrict__ easgn, const float* __restrict__ wts,
    short* __restrict__ act, float* __restrict__ out,
    int* __restrict__ done)
{
    const int e    = blockIdx.y;
    const int tile = blockIdx.x;
    const int h0   = tile * 16;
    const int d0   = tile * 16;
    const int tid  = threadIdx.x;
    const int wv   = tid >> 6;
    const int g    = wv & 1;    // gate index (gates phase)
    const int kh   = wv >> 1;   // K half (gates phase)
    const int lane = tid & 63;
    const int n    = lane & 15;
    const int quad = lane >> 4;

    __shared__ float red[4][2][4][64];   // 8 KB
    __shared__ int   toks[LTOK];         // 2 KB (persists into linear phase)
    __shared__ float wsl[LTOK];          // 2 KB
    __shared__ int   lcnt;

    // easgn/wts loads issued FIRST (oldest vmem slots -> scan waits only on them)
    const int4   eg  = ((const int4*)easgn)[tid];
    const float4 wt4 = ((const float4*)wts)[tid];

    // ---- G register stage: 16 x global_load_dwordx4 per lane ----
    const float* Gl = G + ((size_t)((e * 2 + g) * HDIM) + h0 + n) * DDIM + kh * 256 + quad * 8;
    floatx4 u0[8], u1[8];
#pragma unroll
    for (int ks = 0; ks < 8; ++ks) {
        u0[ks] = *(const floatx4*)(Gl + ks * 32);
        u1[ks] = *(const floatx4*)(Gl + ks * 32 + 4);
    }

    // ---- self-select scan (once; reused by linear), under the G flight ----
    if (tid == 0) lcnt = 0;
    RAW_BARRIER();
    if (eg.x == e) { int p = atomicAdd(&lcnt, 1); toks[p] = 4 * tid;     wsl[p] = wt4.x; }
    if (eg.y == e) { int p = atomicAdd(&lcnt, 1); toks[p] = 4 * tid + 1; wsl[p] = wt4.y; }
    if (eg.z == e) { int p = atomicAdd(&lcnt, 1); toks[p] = 4 * tid + 2; wsl[p] = wt4.z; }
    if (eg.w == e) { int p = atomicAdd(&lcnt, 1); toks[p] = 4 * tid + 3; wsl[p] = wt4.w; }
    RAW_BARRIER();
    const int Ne = lcnt;

    // ---- pack gates B fragments (G regs die here) ----
    short8 Bg[8];
#pragma unroll
    for (int ks = 0; ks < 8; ++ks) {
        union { short8 s; unsigned u[4]; } B;
        B.u[0] = bpack(u0[ks].x, u0[ks].y);
        B.u[1] = bpack(u0[ks].z, u0[ks].w);
        B.u[2] = bpack(u1[ks].x, u1[ks].y);
        B.u[3] = bpack(u1[ks].z, u1[ks].w);
        Bg[ks] = B.s;
    }

    // ================= gates phase =================
    if (Ne > 0) {
        const short* xbh = xb + kh * 256;
        for (int mb = 0; mb < Ne; mb += 32) {
            int arow[2];
#pragma unroll
            for (int i = 0; i < 2; ++i) {
                int s = mb + i * 16 + n;
                arow[i] = toks[s < Ne ? s : Ne - 1] >> 1;   // token index
            }
            floatx4 acc[2] = {};
#pragma unroll
            for (int ks = 0; ks < 8; ++ks) {
                const int ko = ks * 32 + quad * 8;
#pragma unroll
                for (int i = 0; i < 2; ++i) {
                    const short8 A = *(const short8*)(xbh + (size_t)arow[i] * DDIM + ko);
                    acc[i] = __builtin_amdgcn_mfma_f32_16x16x32_bf16(A, Bg[ks], acc[i], 0, 0, 0);
                }
            }
#pragma unroll
            for (int i = 0; i < 2; ++i)
#pragma unroll
                for (int r = 0; r < 4; ++r)
                    red[wv][i][r][lane] = acc[i][r];
            __syncthreads();

            // epilogue: wave handles m-tile (wv&1), regs {2u,2u+1}, u=wv>>1.
            // act store is sc0 sc1 write-through -> lands at MALL, no fence
            // needed later.
            {
                const int i = wv & 1;
                const int u = wv >> 1;
#pragma unroll
                for (int rr = 0; rr < 2; ++rr) {
                    const int r = u * 2 + rr;
                    const int s = mb + i * 16 + quad * 4 + r;
                    if (s < Ne) {
                        const int a = toks[s];   // slot id = act row
                        const float g0 = red[0][i][r][lane] + red[2][i][r][lane];
                        const float g1 = red[1][i][r][lane] + red[3][i][r][lane];
                        const float uu = 0.7978845608f * (g0 + 0.044715f * g0 * g0 * g0);
                        const float sg = 1.0f / (1.0f + __expf(-2.0f * uu));
                        const float v = g0 * sg * g1;
                        mall_store_b16(act + (size_t)a * HDIM + h0 + n,
                                       bpack(v, 0.f) & 0xFFFFu);
                    }
                }
            }
            __syncthreads();
        }
    }

    // ---- release: act stores reached MALL (vmcnt 0), then ONE relaxed atomic ----
    asm volatile("s_waitcnt vmcnt(0)" ::: "memory");
    __syncthreads();
    if (tid == 0)
        __hip_atomic_fetch_add(&done[e], 1, __ATOMIC_RELAXED, __HIP_MEMORY_SCOPE_AGENT);

    if (Ne == 0) return;      // arrived already; nothing to do in linear

    // ---- Wl register stage issued BEFORE the wait (latency hides under it) ----
    const float* Wbase = Wl + ((size_t)e * HDIM + wv * 128 + quad * 8) * DDIM + d0 + n;
    float w[32];
#pragma unroll
    for (int ks = 0; ks < 4; ++ks)
#pragma unroll
        for (int j = 0; j < 8; ++j)
            w[ks * 8 + j] = Wbase[(size_t)(ks * 32 + j) * DDIM];

    // ---- wait: RELAXED spin (no L2 maintenance at all) ----
    if (tid == 0) {
        while (__hip_atomic_load(&done[e], __ATOMIC_RELAXED, __HIP_MEMORY_SCOPE_AGENT) < NEXP)
            __builtin_amdgcn_s_sleep(2);
    }
    __syncthreads();   // block-level fence: orders the MALL act reads below

    // ---- pack linear B fragments ----
    short8 Bl[4];
#pragma unroll
    for (int ks = 0; ks < 4; ++ks) {
        union { short8 s; unsigned u[4]; } B;
        B.u[0] = bpack(w[ks * 8 + 0], w[ks * 8 + 1]);
        B.u[1] = bpack(w[ks * 8 + 2], w[ks * 8 + 3]);
        B.u[2] = bpack(w[ks * 8 + 4], w[ks * 8 + 5]);
        B.u[3] = bpack(w[ks * 8 + 6], w[ks * 8 + 7]);
        Bl[ks] = B.s;
    }

    // ================= linear phase (toks/wsl/Ne reused) =================
    for (int mb = 0; mb < Ne; mb += 32) {
        int arow[2];
#pragma unroll
        for (int i = 0; i < 2; ++i) {
            int s = mb + i * 16 + n;
            arow[i] = toks[s < Ne ? s : Ne - 1];   // slot id = act row
        }
        // batch all 8 MALL A-loads, then one wait (asm loads are not tracked
        // by the compiler's waitcnt insertion), then pin MFMAs after it
        // (rule #18: sched_barrier after an inline-asm waitcnt).
        short8 A[2][4];
#pragma unroll
        for (int ks = 0; ks < 4; ++ks) {
            const int ko = wv * 128 + ks * 32 + quad * 8;
#pragma unroll
            for (int i = 0; i < 2; ++i) {
                union { floatx4 f; short8 s; } t;
                t.f = mall_load_b128(act + (size_t)arow[i] * HDIM + ko);
                A[i][ks] = t.s;
            }
        }
        asm volatile("s_waitcnt vmcnt(0)" ::: "memory");
        __builtin_amdgcn_sched_barrier(0);

        floatx4 acc[2] = {};
#pragma unroll
        for (int ks = 0; ks < 4; ++ks)
#pragma unroll
            for (int i = 0; i < 2; ++i)
                acc[i] = __builtin_amdgcn_mfma_f32_16x16x32_bf16(A[i][ks], Bl[ks], acc[i], 0, 0, 0);

#pragma unroll
        for (int i = 0; i < 2; ++i)
#pragma unroll
            for (int r = 0; r < 4; ++r)
                red[wv][i][r][lane] = acc[i][r];
        __syncthreads();

        {
            const int i = wv & 1;
            const int u = wv >> 1;
#pragma unroll
            for (int rr = 0; rr < 2; ++rr) {
                const int r = u * 2 + rr;
                const int s = mb + i * 16 + quad * 4 + r;
                if (s < Ne) {
                    const int slot = toks[s];
                    const float v = ((red[0][i][r][lane] + red[1][i][r][lane]) +
                                     (red[2][i][r][lane] + red[3][i][r][lane])) * wsl[s];
                    atomicAdd(&out[(size_t)(slot >> 1) * DDIM + d0 + n], v);
                }
            }
        }
        __syncthreads();
    }
}

extern "C" void kernel_launch(void* const* d_in, const int* in_sizes, int n_in,
                              void* d_out, int out_size, void* d_ws, size_t ws_size,
                              hipStream_t stream)
{
    const float* x   = (const float*)d_in[0];
    const float* rs  = (const float*)d_in[1];
    const float* Wr  = (const float*)d_in[2];
    const float* G   = (const float*)d_in[3];
    const float* Wl  = (const float*)d_in[4];
    const float* pes = (const float*)d_in[5];
    float* out = (float*)d_out;

    char* ws = (char*)d_ws;
    int*   easgn = (int*)(ws);
    float* wts   = (float*)(ws + 4096);
    short* xb    = (short*)(ws + 8192);
    short* act   = (short*)(ws + 532480);
    int*   done  = (int*)(ws + 1581056);

    router_kernel<<<dim3(LTOK), dim3(256), 0, stream>>>(x, rs, Wr, pes, easgn, wts, xb, out, done);
    expert_kernel<<<dim3(32, NEXP), dim3(256), 0, stream>>>(xb, G, Wl, easgn, wts, act, out, done);
}

// Round 7
// 159.796 us; speedup vs baseline: 2.5390x; 1.2404x over previous
//
#include <hip/hip_runtime.h>
#include <hip/hip_bf16.h>
#include <math.h>

#define LTOK 512
#define DDIM 512
#define NEXP 32
#define HDIM 512

typedef __attribute__((ext_vector_type(8))) short short8;
typedef __attribute__((ext_vector_type(4))) float floatx4;

// round-to-nearest-even fp32->bf16, packed pair: low16 = rne(a), high16 = rne(b)
__device__ __forceinline__ unsigned bpack(float a, float b) {
    unsigned ua = __float_as_uint(a), ub = __float_as_uint(b);
    ua += 0x7FFFu + ((ua >> 16) & 1u);
    ub += 0x7FFFu + ((ub >> 16) & 1u);
    return (ua >> 16) | (ub & 0xFFFF0000u);
}

// Raw barrier WITHOUT the compiler's s_waitcnt vmcnt(0) drain (so in-flight
// weight loads stay in flight across it). Own-wave LDS ops drained.
#define RAW_BARRIER() do { \
    asm volatile("s_waitcnt lgkmcnt(0)" ::: "memory"); \
    __builtin_amdgcn_s_barrier(); \
} while (0)

// ws layout (bytes):
//   [0, 4K)        easgn: int[1024]   easgn[2t+k] = expert of token t's k-th pick
//   [4K, 8K)       wts:   float[1024] = routing weight * per_expert_scale
//   [8K, +512K)    xb:    512x512 bf16 (x rounded to bf16)
//   [532480, +1M)  act:   1024x512 bf16 (slot-indexed activated gate output)

// grid 1024: blocks < 512 route one token each (4 waves split the logits
// K-dim: 64 Wr loads/lane). Blocks >= 512 are G-WARM blocks: the router uses
// only 2 blocks/CU, so the other half of the machine streams all 524288
// 128-B lines of G (64 MB) into the memory-side MALL, fully overlapped with
// router compute. gates_kernel's G register-stage then hits MALL instead of
// cold HBM. Read-only, no sync, no correctness coupling.
__global__ __launch_bounds__(256) void router_kernel(
    const float* __restrict__ x, const float* __restrict__ rs,
    const float* __restrict__ Wr, const float* __restrict__ pes,
    const float* __restrict__ G,
    int* __restrict__ easgn, float* __restrict__ wts,
    short* __restrict__ xb, float* __restrict__ out)
{
    const int t = blockIdx.x;
    const int tid = threadIdx.x;

    if (t >= LTOK) {
        // ---- G-warm: one dword per 128-B line, wave = 64 lines/instr ----
        const int w = (t - LTOK) * 256 + tid;            // 0..131071
        const float* p = G + (size_t)w * 32;             // 128-B line stride
#pragma unroll
        for (int k = 0; k < 4; ++k) {                    // 4*131072 = 524288 lines
            float v = p[(size_t)k * 131072 * 32];
            asm volatile("" :: "v"(v));                  // keep-alive (rule #17)
        }
        return;
    }

    const int lane = tid & 63;
    const int wv = tid >> 6;

    float xv[2];
    float ss = 0.f;
#pragma unroll
    for (int j = 0; j < 2; ++j) {
        xv[j] = x[t * DDIM + j * 256 + tid];
        ss += xv[j] * xv[j];
    }
    // emit bf16 copy of x for the expert GEMMs; zero this token's out row
#pragma unroll
    for (int j = 0; j < 2; ++j) {
        xb[t * DDIM + j * 256 + tid] = (short)(bpack(xv[j], 0.f) & 0xFFFFu);
        out[t * DDIM + j * 256 + tid] = 0.f;
    }

#pragma unroll
    for (int o = 32; o > 0; o >>= 1) ss += __shfl_xor(ss, o);
    __shared__ float sred[4];
    if (lane == 0) sred[wv] = ss;
    __syncthreads();
    ss = (sred[0] + sred[1]) + (sred[2] + sred[3]);
    const float var = ss * (1.0f / 512.0f);
    const float coef = rsqrtf(var + 1e-6f) * rsqrtf(512.0f);

    __shared__ float ri[DDIM];
#pragma unroll
    for (int j = 0; j < 2; ++j) {
        const int d = j * 256 + tid;
        ri[d] = xv[j] * coef * rs[d];
    }
    __syncthreads();

    // logits: tid&31 -> expert, tid>>5 -> 1/8th of D (64 d each)
    const int e = tid & 31;
    const int seg = tid >> 5;
    const int dbeg = seg * 64;
    float l0 = 0.f, l1 = 0.f, l2 = 0.f, l3 = 0.f;
#pragma unroll 4
    for (int d = dbeg; d < dbeg + 64; d += 4) {
        l0 = fmaf(ri[d + 0], Wr[(d + 0) * NEXP + e], l0);
        l1 = fmaf(ri[d + 1], Wr[(d + 1) * NEXP + e], l1);
        l2 = fmaf(ri[d + 2], Wr[(d + 2) * NEXP + e], l2);
        l3 = fmaf(ri[d + 3], Wr[(d + 3) * NEXP + e], l3);
    }
    __shared__ float lpart[8][NEXP];
    lpart[seg][e] = (l0 + l1) + (l2 + l3);
    __syncthreads();

    __shared__ float lgs[NEXP];
    if (tid < NEXP) {
        float v = 0.f;
#pragma unroll
        for (int s = 0; s < 8; ++s) v += lpart[s][tid];
        lgs[tid] = v;
    }
    __syncthreads();

    if (tid == 0) {
        int i0 = 0; float m0 = lgs[0];
        for (int i = 1; i < NEXP; ++i) if (lgs[i] > m0) { m0 = lgs[i]; i0 = i; }
        int i1 = -1; float m1 = -1e30f;
        for (int i = 0; i < NEXP; ++i) if (i != i0 && lgs[i] > m1) { m1 = lgs[i]; i1 = i; }
        // softmax denom cancels against renorm: weights depend only on top-2 logits
        const float e1 = expf(m1 - m0);
        const float inv = 1.0f / (1.0f + e1);
        easgn[2 * t]     = i0;
        easgn[2 * t + 1] = i1;
        wts[2 * t]     = inv * pes[i0];
        wts[2 * t + 1] = e1 * inv * pes[i1];
    }
}

// grid (32, 32): blockIdx.x = 16-wide h tile, blockIdx.y = expert.
// 4 waves: wv = (khalf<<1)|gate. Register staging: the wave's B chunk
// (16 h x 256 k fp32) is loaded straight to VGPRs (16 x dwordx4/lane) and
// bpack'd from regs. G is MALL-warm from the router's warm blocks.
// Scan overlap: eg issued first, scan waits only on it (raw barriers keep
// the compiler's vmcnt(0) drain out); weight loads stay in flight under it.
__global__ __launch_bounds__(256, 4) void gates_kernel(
    const short* __restrict__ xb, const float* __restrict__ G,
    const int* __restrict__ easgn, short* __restrict__ act)
{
    const int e  = blockIdx.y;
    const int h0 = blockIdx.x * 16;
    const int tid = threadIdx.x;
    const int wv   = tid >> 6;
    const int g    = wv & 1;    // gate index
    const int kh   = wv >> 1;   // K half
    const int lane = tid & 63;
    const int n    = lane & 15;
    const int quad = lane >> 4;

    __shared__ float red[4][2][4][64];   // 8 KB
    __shared__ int toks[LTOK];           // 2 KB
    __shared__ int lcnt;

    // easgn load issued FIRST (oldest vmem slot -> scan waits only on it)
    const int4 eg = ((const int4*)easgn)[tid];

    // ---- register stage: 16 x global_load_dwordx4 per lane ----
    const float* Gl = G + ((size_t)((e * 2 + g) * HDIM) + h0 + n) * DDIM + kh * 256 + quad * 8;
    floatx4 u0[8], u1[8];
#pragma unroll
    for (int ks = 0; ks < 8; ++ks) {
        u0[ks] = *(const floatx4*)(Gl + ks * 32);
        u1[ks] = *(const floatx4*)(Gl + ks * 32 + 4);
    }

    // ---- self-select scan, overlapped with the weight-load flight ----
    if (tid == 0) lcnt = 0;
    RAW_BARRIER();
    if (eg.x == e) { int p = atomicAdd(&lcnt, 1); toks[p] = 4 * tid; }
    if (eg.y == e) { int p = atomicAdd(&lcnt, 1); toks[p] = 4 * tid + 1; }
    if (eg.z == e) { int p = atomicAdd(&lcnt, 1); toks[p] = 4 * tid + 2; }
    if (eg.w == e) { int p = atomicAdd(&lcnt, 1); toks[p] = 4 * tid + 3; }
    RAW_BARRIER();
    const int Ne = lcnt;
    if (Ne == 0) return;   // reg loads drain automatically at wave end

    // ---- pack to MFMA B fragments (compiler inserts per-use vmcnt waits) ----
    short8 Bg[8];
#pragma unroll
    for (int ks = 0; ks < 8; ++ks) {
        union { short8 s; unsigned u[4]; } B;
        B.u[0] = bpack(u0[ks].x, u0[ks].y);
        B.u[1] = bpack(u0[ks].z, u0[ks].w);
        B.u[2] = bpack(u1[ks].x, u1[ks].y);
        B.u[3] = bpack(u1[ks].z, u1[ks].w);
        Bg[ks] = B.s;
    }

    const short* xbh = xb + kh * 256;

    for (int mb = 0; mb < Ne; mb += 32) {
        int arow[2];
#pragma unroll
        for (int i = 0; i < 2; ++i) {
            int s = mb + i * 16 + n;
            arow[i] = toks[s < Ne ? s : Ne - 1] >> 1;   // token index
        }
        floatx4 acc[2] = {};
#pragma unroll
        for (int ks = 0; ks < 8; ++ks) {
            const int ko = ks * 32 + quad * 8;
#pragma unroll
            for (int i = 0; i < 2; ++i) {
                const short8 A = *(const short8*)(xbh + (size_t)arow[i] * DDIM + ko);
                acc[i] = __builtin_amdgcn_mfma_f32_16x16x32_bf16(A, Bg[ks], acc[i], 0, 0, 0);
            }
        }
#pragma unroll
        for (int i = 0; i < 2; ++i)
#pragma unroll
            for (int r = 0; r < 4; ++r)
                red[wv][i][r][lane] = acc[i][r];
        __syncthreads();

        // epilogue: wave handles m-tile (wv&1), regs {2u,2u+1}, u=wv>>1.
        // C/D: col = lane&15, row = quad*4 + r.
        {
            const int i = wv & 1;
            const int u = wv >> 1;
#pragma unroll
            for (int rr = 0; rr < 2; ++rr) {
                const int r = u * 2 + rr;
                const int s = mb + i * 16 + quad * 4 + r;
                if (s < Ne) {
                    const int a = toks[s];   // slot id = act row
                    const float g0 = red[0][i][r][lane] + red[2][i][r][lane];
                    const float g1 = red[1][i][r][lane] + red[3][i][r][lane];
                    // gelu_tanh(g0) = g0 * sigmoid(2*u)
                    const float uu = 0.7978845608f * (g0 + 0.044715f * g0 * g0 * g0);
                    const float sg = 1.0f / (1.0f + __expf(-2.0f * uu));
                    const float v = g0 * sg * g1;
                    act[(size_t)a * HDIM + h0 + n] = (short)(bpack(v, 0.f) & 0xFFFFu);
                }
            }
        }
        __syncthreads();
    }
}

// grid (32, 32): blockIdx.x = 16-wide d tile, blockIdx.y = expert.
// 4 waves = K quarters (128 h). Register staging: 32 strided scalar loads/lane.
// Scan overlap preserved (eg/wt4 issued first).
__global__ __launch_bounds__(256, 4) void linear_kernel(
    const short* __restrict__ act, const float* __restrict__ Wl,
    const int* __restrict__ easgn, const float* __restrict__ wts,
    float* __restrict__ out)
{
    const int e  = blockIdx.y;
    const int d0 = blockIdx.x * 16;
    const int tid = threadIdx.x;
    const int wv   = tid >> 6;
    const int lane = tid & 63;
    const int n    = lane & 15;
    const int quad = lane >> 4;

    __shared__ float red[4][2][4][64];   // 8 KB
    __shared__ int   toks[LTOK];
    __shared__ float wsl[LTOK];
    __shared__ int   lcnt;

    // issued first: oldest vmem slots
    const int4 eg = ((const int4*)easgn)[tid];
    const float4 wt4 = ((const float4*)wts)[tid];

    // ---- register stage: 32 strided scalar loads per lane ----
    const float* Wbase = Wl + ((size_t)e * HDIM + wv * 128 + quad * 8) * DDIM + d0 + n;
    float w[32];
#pragma unroll
    for (int ks = 0; ks < 4; ++ks)
#pragma unroll
        for (int j = 0; j < 8; ++j)
            w[ks * 8 + j] = Wbase[(size_t)(ks * 32 + j) * DDIM];

    // ---- self-select scan, overlapped with the weight-load flight ----
    if (tid == 0) lcnt = 0;
    RAW_BARRIER();
    if (eg.x == e) { int p = atomicAdd(&lcnt, 1); toks[p] = 4 * tid;     wsl[p] = wt4.x; }
    if (eg.y == e) { int p = atomicAdd(&lcnt, 1); toks[p] = 4 * tid + 1; wsl[p] = wt4.y; }
    if (eg.z == e) { int p = atomicAdd(&lcnt, 1); toks[p] = 4 * tid + 2; wsl[p] = wt4.z; }
    if (eg.w == e) { int p = atomicAdd(&lcnt, 1); toks[p] = 4 * tid + 3; wsl[p] = wt4.w; }
    RAW_BARRIER();
    const int Ne = lcnt;
    if (Ne == 0) return;

    // ---- pack (compiler inserts per-use vmcnt waits) ----
    short8 Bl[4];
#pragma unroll
    for (int ks = 0; ks < 4; ++ks) {
        union { short8 s; unsigned u[4]; } B;
        B.u[0] = bpack(w[ks * 8 + 0], w[ks * 8 + 1]);
        B.u[1] = bpack(w[ks * 8 + 2], w[ks * 8 + 3]);
        B.u[2] = bpack(w[ks * 8 + 4], w[ks * 8 + 5]);
        B.u[3] = bpack(w[ks * 8 + 6], w[ks * 8 + 7]);
        Bl[ks] = B.s;
    }

    for (int mb = 0; mb < Ne; mb += 32) {
        int arow[2];
#pragma unroll
        for (int i = 0; i < 2; ++i) {
            int s = mb + i * 16 + n;
            arow[i] = toks[s < Ne ? s : Ne - 1];   // slot id = act row
        }
        floatx4 acc[2] = {};
#pragma unroll
        for (int ks = 0; ks < 4; ++ks) {
            const int ko = wv * 128 + ks * 32 + quad * 8;
#pragma unroll
            for (int i = 0; i < 2; ++i) {
                const short8 A = *(const short8*)(act + (size_t)arow[i] * HDIM + ko);
                acc[i] = __builtin_amdgcn_mfma_f32_16x16x32_bf16(A, Bl[ks], acc[i], 0, 0, 0);
            }
        }
#pragma unroll
        for (int i = 0; i < 2; ++i)
#pragma unroll
            for (int r = 0; r < 4; ++r)
                red[wv][i][r][lane] = acc[i][r];
        __syncthreads();

        {
            const int i = wv & 1;
            const int u = wv >> 1;
#pragma unroll
            for (int rr = 0; rr < 2; ++rr) {
                const int r = u * 2 + rr;
                const int s = mb + i * 16 + quad * 4 + r;
                if (s < Ne) {
                    const int slot = toks[s];
                    const float v = ((red[0][i][r][lane] + red[1][i][r][lane]) +
                                     (red[2][i][r][lane] + red[3][i][r][lane])) * wsl[s];
                    atomicAdd(&out[(size_t)(slot >> 1) * DDIM + d0 + n], v);
                }
            }
        }
        __syncthreads();
    }
}

extern "C" void kernel_launch(void* const* d_in, const int* in_sizes, int n_in,
                              void* d_out, int out_size, void* d_ws, size_t ws_size,
                              hipStream_t stream)
{
    const float* x   = (const float*)d_in[0];
    const float* rs  = (const float*)d_in[1];
    const float* Wr  = (const float*)d_in[2];
    const float* G   = (const float*)d_in[3];
    const float* Wl  = (const float*)d_in[4];
    const float* pes = (const float*)d_in[5];
    float* out = (float*)d_out;

    char* ws = (char*)d_ws;
    int*   easgn = (int*)(ws);
    float* wts   = (float*)(ws + 4096);
    short* xb    = (short*)(ws + 8192);
    short* act   = (short*)(ws + 532480);

    router_kernel<<<dim3(2 * LTOK), dim3(256), 0, stream>>>(x, rs, Wr, pes, G, easgn, wts, xb, out);
    gates_kernel<<<dim3(32, NEXP), dim3(256), 0, stream>>>(xb, G, easgn, act);
    linear_kernel<<<dim3(32, NEXP), dim3(256), 0, stream>>>(act, Wl, easgn, wts, out);
}

// Round 8
// 151.289 us; speedup vs baseline: 2.6817x; 1.0562x over previous
//
#include <hip/hip_runtime.h>
#include <hip/hip_bf16.h>
#include <math.h>

#define LTOK 512
#define DDIM 512
#define NEXP 32
#define HDIM 512

typedef __attribute__((ext_vector_type(8))) short short8;
typedef __attribute__((ext_vector_type(4))) float floatx4;

// round-to-nearest-even fp32->bf16, packed pair: low16 = rne(a), high16 = rne(b)
__device__ __forceinline__ unsigned bpack(float a, float b) {
    unsigned ua = __float_as_uint(a), ub = __float_as_uint(b);
    ua += 0x7FFFu + ((ua >> 16) & 1u);
    ub += 0x7FFFu + ((ub >> 16) & 1u);
    return (ua >> 16) | (ub & 0xFFFF0000u);
}

// Raw barrier WITHOUT the compiler's s_waitcnt vmcnt(0) drain (so in-flight
// weight loads stay in flight across it). Own-wave LDS ops drained for the
// scan's init/publish correctness; "memory" clobber pins LDS op order.
#define RAW_BARRIER() do { \
    asm volatile("s_waitcnt lgkmcnt(0)" ::: "memory"); \
    __builtin_amdgcn_s_barrier(); \
} while (0)

// ws layout (bytes):
//   [0, 4K)        easgn: int[1024]   easgn[2t+k] = expert of token t's k-th pick
//   [4K, 8K)       wts:   float[1024] = routing weight * per_expert_scale
//   [8K, +512K)    xb:    512x512 bf16 (x rounded to bf16)
//   [532480, +1M)  act:   1024x512 bf16 (slot-indexed activated gate output)

// 256 threads/token-block: 4 waves split the logits K-dim (64 Wr loads/lane).
__global__ __launch_bounds__(256) void router_kernel(
    const float* __restrict__ x, const float* __restrict__ rs,
    const float* __restrict__ Wr, const float* __restrict__ pes,
    int* __restrict__ easgn, float* __restrict__ wts,
    short* __restrict__ xb, float* __restrict__ out)
{
    const int t = blockIdx.x;
    const int tid = threadIdx.x;
    const int lane = tid & 63;
    const int wv = tid >> 6;

    float xv[2];
    float ss = 0.f;
#pragma unroll
    for (int j = 0; j < 2; ++j) {
        xv[j] = x[t * DDIM + j * 256 + tid];
        ss += xv[j] * xv[j];
    }
    // emit bf16 copy of x for the expert GEMMs; zero this token's out row
#pragma unroll
    for (int j = 0; j < 2; ++j) {
        xb[t * DDIM + j * 256 + tid] = (short)(bpack(xv[j], 0.f) & 0xFFFFu);
        out[t * DDIM + j * 256 + tid] = 0.f;
    }

#pragma unroll
    for (int o = 32; o > 0; o >>= 1) ss += __shfl_xor(ss, o);
    __shared__ float sred[4];
    if (lane == 0) sred[wv] = ss;
    __syncthreads();
    ss = (sred[0] + sred[1]) + (sred[2] + sred[3]);
    const float var = ss * (1.0f / 512.0f);
    const float coef = rsqrtf(var + 1e-6f) * rsqrtf(512.0f);

    __shared__ float ri[DDIM];
#pragma unroll
    for (int j = 0; j < 2; ++j) {
        const int d = j * 256 + tid;
        ri[d] = xv[j] * coef * rs[d];
    }
    __syncthreads();

    // logits: tid&31 -> expert, tid>>5 -> 1/8th of D (64 d each)
    const int e = tid & 31;
    const int seg = tid >> 5;
    const int dbeg = seg * 64;
    float l0 = 0.f, l1 = 0.f, l2 = 0.f, l3 = 0.f;
#pragma unroll 4
    for (int d = dbeg; d < dbeg + 64; d += 4) {
        l0 = fmaf(ri[d + 0], Wr[(d + 0) * NEXP + e], l0);
        l1 = fmaf(ri[d + 1], Wr[(d + 1) * NEXP + e], l1);
        l2 = fmaf(ri[d + 2], Wr[(d + 2) * NEXP + e], l2);
        l3 = fmaf(ri[d + 3], Wr[(d + 3) * NEXP + e], l3);
    }
    __shared__ float lpart[8][NEXP];
    lpart[seg][e] = (l0 + l1) + (l2 + l3);
    __syncthreads();

    __shared__ float lgs[NEXP];
    if (tid < NEXP) {
        float v = 0.f;
#pragma unroll
        for (int s = 0; s < 8; ++s) v += lpart[s][tid];
        lgs[tid] = v;
    }
    __syncthreads();

    if (tid == 0) {
        int i0 = 0; float m0 = lgs[0];
        for (int i = 1; i < NEXP; ++i) if (lgs[i] > m0) { m0 = lgs[i]; i0 = i; }
        int i1 = -1; float m1 = -1e30f;
        for (int i = 0; i < NEXP; ++i) if (i != i0 && lgs[i] > m1) { m1 = lgs[i]; i1 = i; }
        // softmax denom cancels against renorm: weights depend only on top-2 logits
        const float e1 = expf(m1 - m0);
        const float inv = 1.0f / (1.0f + e1);
        easgn[2 * t]     = i0;
        easgn[2 * t + 1] = i1;
        wts[2 * t]     = inv * pes[i0];
        wts[2 * t + 1] = e1 * inv * pes[i1];
    }
}

// grid (32, 32): blockIdx.x = 16-wide h tile, blockIdx.y = expert.
// 4 waves: wv = (khalf<<1)|gate. Register staging: the wave's B chunk
// (16 h x 256 k fp32) is loaded straight to VGPRs (16 x dwordx4/lane,
// 64 B HBM granules fully used) and bpack'd from regs — no LDS stage, no
// DMA->LDS->ds_read hop. LDS 10.3 KB; launch_bounds(256,4) -> 4 blocks/CU
// -> all 1024 blocks resident (one residency round).
// Scan overlap: eg issued first, scan waits vmcnt(#weights) only (compiler
// per-use waits); weight loads stay in flight under it (raw barriers keep
// the compiler's vmcnt(0) drain out).
__global__ __launch_bounds__(256, 4) void gates_kernel(
    const short* __restrict__ xb, const float* __restrict__ G,
    const int* __restrict__ easgn, short* __restrict__ act)
{
    const int e  = blockIdx.y;
    const int h0 = blockIdx.x * 16;
    const int tid = threadIdx.x;
    const int wv   = tid >> 6;
    const int g    = wv & 1;    // gate index
    const int kh   = wv >> 1;   // K half
    const int lane = tid & 63;
    const int n    = lane & 15;
    const int quad = lane >> 4;

    __shared__ float red[4][2][4][64];   // 8 KB
    __shared__ int toks[LTOK];           // 2 KB
    __shared__ int lcnt;

    // easgn load issued FIRST (oldest vmem slot -> scan waits only on it)
    const int4 eg = ((const int4*)easgn)[tid];

    // ---- register stage: 16 x global_load_dwordx4 per lane ----
    const float* Gl = G + ((size_t)((e * 2 + g) * HDIM) + h0 + n) * DDIM + kh * 256 + quad * 8;
    floatx4 u0[8], u1[8];
#pragma unroll
    for (int ks = 0; ks < 8; ++ks) {
        u0[ks] = *(const floatx4*)(Gl + ks * 32);
        u1[ks] = *(const floatx4*)(Gl + ks * 32 + 4);
    }

    // ---- self-select scan, overlapped with the weight-load flight ----
    if (tid == 0) lcnt = 0;
    RAW_BARRIER();
    if (eg.x == e) { int p = atomicAdd(&lcnt, 1); toks[p] = 4 * tid; }
    if (eg.y == e) { int p = atomicAdd(&lcnt, 1); toks[p] = 4 * tid + 1; }
    if (eg.z == e) { int p = atomicAdd(&lcnt, 1); toks[p] = 4 * tid + 2; }
    if (eg.w == e) { int p = atomicAdd(&lcnt, 1); toks[p] = 4 * tid + 3; }
    RAW_BARRIER();
    const int Ne = lcnt;
    if (Ne == 0) return;   // reg loads drain automatically at wave end

    // ---- pack to MFMA B fragments (compiler inserts per-use vmcnt waits) ----
    short8 Bg[8];
#pragma unroll
    for (int ks = 0; ks < 8; ++ks) {
        union { short8 s; unsigned u[4]; } B;
        B.u[0] = bpack(u0[ks].x, u0[ks].y);
        B.u[1] = bpack(u0[ks].z, u0[ks].w);
        B.u[2] = bpack(u1[ks].x, u1[ks].y);
        B.u[3] = bpack(u1[ks].z, u1[ks].w);
        Bg[ks] = B.s;
    }

    const short* xbh = xb + kh * 256;

    for (int mb = 0; mb < Ne; mb += 32) {
        int arow[2];
#pragma unroll
        for (int i = 0; i < 2; ++i) {
            int s = mb + i * 16 + n;
            arow[i] = toks[s < Ne ? s : Ne - 1] >> 1;   // token index
        }
        floatx4 acc[2] = {};
#pragma unroll
        for (int ks = 0; ks < 8; ++ks) {
            const int ko = ks * 32 + quad * 8;
#pragma unroll
            for (int i = 0; i < 2; ++i) {
                const short8 A = *(const short8*)(xbh + (size_t)arow[i] * DDIM + ko);
                acc[i] = __builtin_amdgcn_mfma_f32_16x16x32_bf16(A, Bg[ks], acc[i], 0, 0, 0);
            }
        }
#pragma unroll
        for (int i = 0; i < 2; ++i)
#pragma unroll
            for (int r = 0; r < 4; ++r)
                red[wv][i][r][lane] = acc[i][r];
        __syncthreads();

        // epilogue: wave handles m-tile (wv&1), regs {2u,2u+1}, u=wv>>1.
        // C/D: col = lane&15, row = quad*4 + r.
        {
            const int i = wv & 1;
            const int u = wv >> 1;
#pragma unroll
            for (int rr = 0; rr < 2; ++rr) {
                const int r = u * 2 + rr;
                const int s = mb + i * 16 + quad * 4 + r;
                if (s < Ne) {
                    const int a = toks[s];   // slot id = act row
                    const float g0 = red[0][i][r][lane] + red[2][i][r][lane];
                    const float g1 = red[1][i][r][lane] + red[3][i][r][lane];
                    // gelu_tanh(g0) = g0 * sigmoid(2*u)
                    const float uu = 0.7978845608f * (g0 + 0.044715f * g0 * g0 * g0);
                    const float sg = 1.0f / (1.0f + __expf(-2.0f * uu));
                    const float v = g0 * sg * g1;
                    act[(size_t)a * HDIM + h0 + n] = (short)(bpack(v, 0.f) & 0xFFFFu);
                }
            }
        }
        __syncthreads();
    }
}

// grid (32, 32): blockIdx.x = 16-wide d tile, blockIdx.y = expert.
// 4 waves = K quarters (128 h). Register staging: 32 strided scalar loads/lane
// (4x64B segments per instr, every byte consumed across the d-tile grid).
// LDS 12.3 KB; 4 blocks/CU -> all 1024 blocks resident. Scan overlap
// preserved (eg/wt4 issued first).
__global__ __launch_bounds__(256, 4) void linear_kernel(
    const short* __restrict__ act, const float* __restrict__ Wl,
    const int* __restrict__ easgn, const float* __restrict__ wts,
    float* __restrict__ out)
{
    const int e  = blockIdx.y;
    const int d0 = blockIdx.x * 16;
    const int tid = threadIdx.x;
    const int wv   = tid >> 6;
    const int lane = tid & 63;
    const int n    = lane & 15;
    const int quad = lane >> 4;

    __shared__ float red[4][2][4][64];   // 8 KB
    __shared__ int   toks[LTOK];
    __shared__ float wsl[LTOK];
    __shared__ int   lcnt;

    // issued first: oldest vmem slots
    const int4 eg = ((const int4*)easgn)[tid];
    const float4 wt4 = ((const float4*)wts)[tid];

    // ---- register stage: 32 strided scalar loads per lane ----
    const float* Wbase = Wl + ((size_t)e * HDIM + wv * 128 + quad * 8) * DDIM + d0 + n;
    float w[32];
#pragma unroll
    for (int ks = 0; ks < 4; ++ks)
#pragma unroll
        for (int j = 0; j < 8; ++j)
            w[ks * 8 + j] = Wbase[(size_t)(ks * 32 + j) * DDIM];

    // ---- self-select scan, overlapped with the weight-load flight ----
    if (tid == 0) lcnt = 0;
    RAW_BARRIER();
    if (eg.x == e) { int p = atomicAdd(&lcnt, 1); toks[p] = 4 * tid;     wsl[p] = wt4.x; }
    if (eg.y == e) { int p = atomicAdd(&lcnt, 1); toks[p] = 4 * tid + 1; wsl[p] = wt4.y; }
    if (eg.z == e) { int p = atomicAdd(&lcnt, 1); toks[p] = 4 * tid + 2; wsl[p] = wt4.z; }
    if (eg.w == e) { int p = atomicAdd(&lcnt, 1); toks[p] = 4 * tid + 3; wsl[p] = wt4.w; }
    RAW_BARRIER();
    const int Ne = lcnt;
    if (Ne == 0) return;

    // ---- pack (compiler inserts per-use vmcnt waits) ----
    short8 Bl[4];
#pragma unroll
    for (int ks = 0; ks < 4; ++ks) {
        union { short8 s; unsigned u[4]; } B;
        B.u[0] = bpack(w[ks * 8 + 0], w[ks * 8 + 1]);
        B.u[1] = bpack(w[ks * 8 + 2], w[ks * 8 + 3]);
        B.u[2] = bpack(w[ks * 8 + 4], w[ks * 8 + 5]);
        B.u[3] = bpack(w[ks * 8 + 6], w[ks * 8 + 7]);
        Bl[ks] = B.s;
    }

    for (int mb = 0; mb < Ne; mb += 32) {
        int arow[2];
#pragma unroll
        for (int i = 0; i < 2; ++i) {
            int s = mb + i * 16 + n;
            arow[i] = toks[s < Ne ? s : Ne - 1];   // slot id = act row
        }
        floatx4 acc[2] = {};
#pragma unroll
        for (int ks = 0; ks < 4; ++ks) {
            const int ko = wv * 128 + ks * 32 + quad * 8;
#pragma unroll
            for (int i = 0; i < 2; ++i) {
                const short8 A = *(const short8*)(act + (size_t)arow[i] * HDIM + ko);
                acc[i] = __builtin_amdgcn_mfma_f32_16x16x32_bf16(A, Bl[ks], acc[i], 0, 0, 0);
            }
        }
#pragma unroll
        for (int i = 0; i < 2; ++i)
#pragma unroll
            for (int r = 0; r < 4; ++r)
                red[wv][i][r][lane] = acc[i][r];
        __syncthreads();

        {
            const int i = wv & 1;
            const int u = wv >> 1;
#pragma unroll
            for (int rr = 0; rr < 2; ++rr) {
                const int r = u * 2 + rr;
                const int s = mb + i * 16 + quad * 4 + r;
                if (s < Ne) {
                    const int slot = toks[s];
                    const float v = ((red[0][i][r][lane] + red[1][i][r][lane]) +
                                     (red[2][i][r][lane] + red[3][i][r][lane])) * wsl[s];
                    atomicAdd(&out[(size_t)(slot >> 1) * DDIM + d0 + n], v);
                }
            }
        }
        __syncthreads();
    }
}

extern "C" void kernel_launch(void* const* d_in, const int* in_sizes, int n_in,
                              void* d_out, int out_size, void* d_ws, size_t ws_size,
                              hipStream_t stream)
{
    const float* x   = (const float*)d_in[0];
    const float* rs  = (const float*)d_in[1];
    const float* Wr  = (const float*)d_in[2];
    const float* G   = (const float*)d_in[3];
    const float* Wl  = (const float*)d_in[4];
    const float* pes = (const float*)d_in[5];
    float* out = (float*)d_out;

    char* ws = (char*)d_ws;
    int*   easgn = (int*)(ws);
    float* wts   = (float*)(ws + 4096);
    short* xb    = (short*)(ws + 8192);
    short* act   = (short*)(ws + 532480);

    router_kernel<<<dim3(LTOK), dim3(256), 0, stream>>>(x, rs, Wr, pes, easgn, wts, xb, out);
    gates_kernel<<<dim3(32, NEXP), dim3(256), 0, stream>>>(xb, G, easgn, act);
    linear_kernel<<<dim3(32, NEXP), dim3(256), 0, stream>>>(act, Wl, easgn, wts, out);
}